// Round 6
// baseline (1004.547 us; speedup 1.0000x reference)
//
#include <hip/hip_runtime.h>
#include <stdint.h>

#define CONF_T 0.01f
#define NMS_T  0.45f
#define M_TOP  200
#define SM_ROWS 64    // rows per softmax block (64 threads); LDS 20.7 KB -> 7 blocks/CU
#define TK_BS  256    // topk block size
#define TCAP   4096   // topk tie-bin compaction capacity (LDS)

__device__ __forceinline__ uint32_t fkey(float f) {
    uint32_t u = __float_as_uint(f);
    return (u & 0x80000000u) ? ~u : (u | 0x80000000u);
}
__device__ __forceinline__ float fkey_inv(uint32_t k) {
    uint32_t u = (k & 0x80000000u) ? (k & 0x7FFFFFFFu) : ~k;
    return __uint_as_float(u);
}

// Parallel suffix-scan bin selection over nb bins (nb multiple of 256).
// Finds largest bin x with suffix_sum(x) >= want; writes prefix|x<<shift and
// residual want. Must be called by all 256 threads; barriers inside.
__device__ __forceinline__ void suffix_select(
        uint32_t* hist, uint32_t* part, int nb, uint32_t pref, int shift,
        uint32_t wantv, uint32_t* s_prefix, uint32_t* s_want) {
    int tid = threadIdx.x;
    int bpt = nb >> 8;
    int base = tid * bpt;
    uint32_t loc = 0;
    for (int j = 0; j < bpt; j++) loc += hist[base + j];
    part[tid] = loc;
    __syncthreads();
    for (int d = 1; d < 256; d <<= 1) {
        uint32_t y = (tid + d < 256) ? part[tid + d] : 0u;
        __syncthreads();
        part[tid] += y;
        __syncthreads();
    }
    uint32_t run = part[tid] - loc;       // suffix sum starting just past my chunk
    for (int j = bpt - 1; j >= 0; j--) {
        uint32_t h = hist[base + j];
        uint32_t sfx = run + h;
        if (run < wantv && sfx >= wantv) { // exactly one (thread,j) satisfies
            *s_prefix = pref | ((uint32_t)(base + j) << shift);
            *s_want   = wantv - run;
        }
        run = sfx;
    }
    __syncthreads();
}

// ---------------- Kernel A: decode boxes ----------------
__global__ __launch_bounds__(256) void decode_kernel(
        const float* __restrict__ loc, const float* __restrict__ dbox,
        float* __restrict__ boxes, int B, int N) {
    int i = blockIdx.x * blockDim.x + threadIdx.x;
    if (i >= B * N) return;
    int n = i % N;
    float4 l = ((const float4*)loc)[i];
    float4 d = ((const float4*)dbox)[n];
    float cx = d.x + (l.x * 0.1f) * d.z;
    float cy = d.y + (l.y * 0.1f) * d.w;
    float w  = d.z * expf(l.z * 0.2f);
    float h  = d.w * expf(l.w * 0.2f);
    float x1 = cx - w * 0.5f, y1 = cy - h * 0.5f;
    float x2 = x1 + w, y2 = y1 + h;
    float4 o;
    o.x = fminf(fmaxf(x1, 0.f), 1.f);
    o.y = fminf(fmaxf(y1, 0.f), 1.f);
    o.z = fminf(fmaxf(x2, 0.f), 1.f);
    o.w = fminf(fmaxf(y2, 0.f), 1.f);
    ((float4*)boxes)[i] = o;
}

// ---------------- Kernel B: softmax + transpose (64-row blocks) ----------------
__global__ __launch_bounds__(SM_ROWS) void softmax_kernel(
        const float* __restrict__ conf, float* __restrict__ sc,
        int B, int N, int C) {
    __shared__ float rows[SM_ROWS * 81];
    int tid = threadIdx.x;
    int BN = B * N;
    long long r0 = (long long)blockIdx.x * SM_ROWS;
    int nrows = BN - (int)r0; if (nrows > SM_ROWS) nrows = SM_ROWS;
    int totalf = nrows * 81;
    const float* g = conf + r0 * 81;
    int total4 = totalf >> 2;
    const float4* g4 = (const float4*)g;
    float4* l4 = (float4*)rows;
    for (int i = tid; i < total4; i += SM_ROWS) l4[i] = g4[i];
    for (int i = (total4 << 2) + tid; i < totalf; i += SM_ROWS) rows[i] = g[i];
    __syncthreads();
    if (tid < nrows) {
        float* p = rows + tid * 81;
        float m = p[0];
        for (int c = 1; c < 81; c++) m = fmaxf(m, p[c]);
        float s = 0.f;
        for (int c = 0; c < 81; c++) { float e = expf(p[c] - m); p[c] = e; s += e; }
        int r = (int)r0 + tid;
        int b = r / N, n = r % N;
        size_t base = ((size_t)b * (C - 1)) * N + n;
        for (int c = 1; c < 81; c++) {
            sc[base + (size_t)(c - 1) * N] = p[c] / s;
        }
    }
}

// ---------------- Kernel C: per-row exact top-200 (2 global sweeps + LDS select) ------
__global__ __launch_bounds__(TK_BS) void topk_kernel(
        const float* __restrict__ sc, const float* __restrict__ boxes,
        float* __restrict__ tk_sc, float* __restrict__ cand,
        int B, int N, int Cm1) {
    const uint32_t KEYN1 = 0x407FFFFFu;        // fkey(-1.0f)
    const uint32_t BIN_N1 = KEYN1 >> 21;       // 0x203
    __shared__ uint32_t hist[2048];
    __shared__ uint32_t part[256];
    __shared__ uint32_t tk[TCAP];              // tie-bin keys
    __shared__ int      tix[TCAP];             // tie-bin indices
    __shared__ uint32_t s_prefix, s_want;
    __shared__ uint32_t ngt, ntie, tcnt;
    __shared__ float    e_val[256];
    __shared__ int      e_idx[256];
    __shared__ int      tiebuf[256];

    int row = blockIdx.x;                      // b*Cm1 + c
    int b = row / Cm1;
    int tid = threadIdx.x;
    const float* v = sc + (size_t)row * N;
    const float4* v4 = (const float4*)v;
    int n4 = N >> 2;

    // ---- phase 1: 2048-bin histogram of top-11 key bits (global sweep 1) ----
    for (int i = tid; i < 2048; i += TK_BS) hist[i] = 0;
    if (tid == 0) { s_prefix = 0; s_want = M_TOP; }
    __syncthreads();
    for (int i = tid; i < n4; i += TK_BS) {
        float4 f = v4[i];
        atomicAdd(&hist[fkey(f.x > CONF_T ? f.x : -1.0f) >> 21], 1u);
        atomicAdd(&hist[fkey(f.y > CONF_T ? f.y : -1.0f) >> 21], 1u);
        atomicAdd(&hist[fkey(f.z > CONF_T ? f.z : -1.0f) >> 21], 1u);
        atomicAdd(&hist[fkey(f.w > CONF_T ? f.w : -1.0f) >> 21], 1u);
    }
    for (int i = (n4 << 2) + tid; i < N; i += TK_BS)
        atomicAdd(&hist[fkey(v[i] > CONF_T ? v[i] : -1.0f) >> 21], 1u);
    __syncthreads();
    suffix_select(hist, part, 2048, 0u, 21, M_TOP, &s_prefix, &s_want);
    uint32_t b0 = s_prefix >> 21;
    uint32_t want1 = s_want;

    // ---- phase 2: compaction (global sweep 2) ----
    if (tid < 256) { e_val[tid] = -1.0f; e_idx[tid] = tid; }
    if (tid == 0) { ngt = 0; ntie = 0; tcnt = 0; }
    __syncthreads();
    bool collect_ties = (b0 != BIN_N1);
    for (int i = tid; i < n4; i += TK_BS) {
        float4 f = v4[i];
        float mv[4] = { f.x > CONF_T ? f.x : -1.0f, f.y > CONF_T ? f.y : -1.0f,
                        f.z > CONF_T ? f.z : -1.0f, f.w > CONF_T ? f.w : -1.0f };
        #pragma unroll
        for (int j = 0; j < 4; j++) {
            uint32_t k = fkey(mv[j]);
            uint32_t bin = k >> 21;
            int idx = 4 * i + j;
            if (bin > b0) {
                uint32_t p = atomicAdd(&ngt, 1u);   // < 200 guaranteed
                if (p < 256) { e_val[p] = mv[j]; e_idx[p] = idx; }
            } else if (bin == b0 && collect_ties) {
                uint32_t p = atomicAdd(&tcnt, 1u);
                if (p < TCAP) { tk[p] = k; tix[p] = idx; }
            }
        }
    }
    for (int i = (n4 << 2) + tid; i < N; i += TK_BS) {
        float f = v[i];
        float mv = f > CONF_T ? f : -1.0f;
        uint32_t k = fkey(mv);
        uint32_t bin = k >> 21;
        if (bin > b0) {
            uint32_t p = atomicAdd(&ngt, 1u);
            if (p < 256) { e_val[p] = mv; e_idx[p] = i; }
        } else if (bin == b0 && collect_ties) {
            uint32_t p = atomicAdd(&tcnt, 1u);
            if (p < TCAP) { tk[p] = k; tix[p] = i; }
        }
    }
    __syncthreads();

    uint32_t kth = KEYN1, rfin = 0;
    if (collect_ties && tcnt <= TCAP) {
        // ---- phase 3: 2-level radix select entirely from the LDS tie buffer ----
        int T = (int)tcnt;
        for (int i = tid; i < 2048; i += TK_BS) hist[i] = 0;
        __syncthreads();
        for (int i = tid; i < T; i += TK_BS) atomicAdd(&hist[(tk[i] >> 10) & 2047u], 1u);
        __syncthreads();
        suffix_select(hist, part, 2048, b0 << 21, 10, want1, &s_prefix, &s_want);
        uint32_t pre2 = s_prefix; uint32_t want2 = s_want;
        uint32_t b1 = (pre2 >> 10) & 2047u;
        for (int i = tid; i < 1024; i += TK_BS) hist[i] = 0;
        __syncthreads();
        for (int i = tid; i < T; i += TK_BS)
            if (((tk[i] >> 10) & 2047u) == b1) atomicAdd(&hist[tk[i] & 1023u], 1u);
        __syncthreads();
        suffix_select(hist, part, 1024, pre2, 0, want2, &s_prefix, &s_want);
        kth = s_prefix; rfin = s_want;
        // collect >kth and ties from LDS buffer
        for (int i = tid; i < T; i += TK_BS) {
            uint32_t k = tk[i];
            if (k > kth) {
                uint32_t p = atomicAdd(&ngt, 1u);
                if (p < 256) { e_val[p] = fkey_inv(k); e_idx[p] = tix[i]; }
            } else if (k == kth) {
                uint32_t p = atomicAdd(&ntie, 1u);
                if (p < 256) tiebuf[p] = tix[i];
            }
        }
        __syncthreads();
    } else if (collect_ties) {
        // ---- overflow fallback: finish radix with global sweeps (rare) ----
        const int shifts[2] = {10, 0};
        const int nbins_[2] = {2048, 1024};
        for (int lev = 0; lev < 2; lev++) {
            int shift = shifts[lev];
            int nb = nbins_[lev];
            uint32_t bmask = (uint32_t)nb - 1u;
            uint32_t pref = s_prefix, wantv = s_want;
            uint32_t pmask = 0xFFFFFFFFu << (shift + ((nb == 2048) ? 11 : 10));
            for (int i = tid; i < nb; i += TK_BS) hist[i] = 0;
            __syncthreads();
            for (int i = tid; i < N; i += TK_BS) {
                float f = v[i];
                uint32_t k = fkey(f > CONF_T ? f : -1.0f);
                if ((k & pmask) == pref) atomicAdd(&hist[(k >> shift) & bmask], 1u);
            }
            __syncthreads();
            suffix_select(hist, part, nb, pref, shift, wantv, &s_prefix, &s_want);
        }
        kth = s_prefix; rfin = s_want;
        for (int i = tid; i < N; i += TK_BS) {
            float f = v[i];
            float mv = f > CONF_T ? f : -1.0f;
            uint32_t k = fkey(mv);
            if ((k >> 21) == b0) {
                if (k > kth) {
                    uint32_t p = atomicAdd(&ngt, 1u);
                    if (p < 256) { e_val[p] = mv; e_idx[p] = i; }
                } else if (k == kth) {
                    uint32_t p = atomicAdd(&ntie, 1u);
                    if (p < 256) tiebuf[p] = i;
                }
            }
        }
        __syncthreads();
    }
    // else: b0 == BIN_N1 -> kth = -1.0, entries = valid ones + (-1,tid) fillers

    uint32_t gcount = min(ngt, (uint32_t)M_TOP);
    if (collect_ties) {
        uint32_t nt = min(ntie, 256u);
        if (tid < (int)nt) {
            int mine = tiebuf[tid];
            uint32_t rk = 0;
            for (uint32_t j = 0; j < nt; j++) if (tiebuf[j] < mine) rk++;
            if (rk < rfin) {
                uint32_t slot = gcount + rk;
                if (slot < M_TOP) { e_val[slot] = fkey_inv(kth); e_idx[slot] = mine; }
            }
        }
    }
    __syncthreads();
    // final stable ordering: (key desc, idx asc) via counting rank
    if (tid < M_TOP) {
        float mv = e_val[tid]; int mi = e_idx[tid];
        uint32_t mk = fkey(mv);
        uint32_t rk = 0;
        for (int j = 0; j < M_TOP; j++) {
            uint32_t jk = fkey(e_val[j]); int ji = e_idx[j];
            if (jk > mk || (jk == mk && ji < mi)) rk++;
        }
        size_t base = (size_t)row * M_TOP + rk;
        tk_sc[base] = mv;
        float4 bb = ((const float4*)boxes)[(size_t)b * N + mi];
        ((float4*)cand)[base] = bb;
    }
}

// ---------------- Kernel D: greedy NMS, one wave per row, register-resident ----------
__global__ __launch_bounds__(64) void nms_kernel(
        const float* __restrict__ tk_sc, const float* __restrict__ cand,
        float* __restrict__ kept) {
    int row = blockIdx.x;
    int lane = threadIdx.x;
    float x1[4], y1[4], x2[4], y2[4], ar[4], sv[4];
    int act[4], kf[4];
    #pragma unroll
    for (int s = 0; s < 4; s++) {
        int j = s * 64 + lane;
        if (j < M_TOP) {
            size_t base = (size_t)row * M_TOP + j;
            float4 bb = ((const float4*)cand)[base];
            x1[s] = bb.x; y1[s] = bb.y; x2[s] = bb.z; y2[s] = bb.w;
            ar[s] = (bb.z - bb.x) * (bb.w - bb.y);
            sv[s] = tk_sc[base];
        } else { x1[s] = 0.f; y1[s] = 0.f; x2[s] = 0.f; y2[s] = 0.f; ar[s] = 0.f; sv[s] = -1.0f; }
        act[s] = (sv[s] > CONF_T) ? 1 : 0;
        kf[s] = 0;
    }
    #pragma unroll
    for (int si = 0; si < 4; si++) {
        int lim = M_TOP - si * 64; if (lim > 64) lim = 64;
        for (int li = 0; li < lim; li++) {
            int a = __shfl(act[si], li);
            if (a) {
                if (lane == li) kf[si] = 1;
                float bx1 = __shfl(x1[si], li);
                float by1 = __shfl(y1[si], li);
                float bx2 = __shfl(x2[si], li);
                float by2 = __shfl(y2[si], li);
                float bar = __shfl(ar[si], li);
                #pragma unroll
                for (int s = 0; s < 4; s++) {
                    float xx1 = fmaxf(bx1, x1[s]);
                    float yy1 = fmaxf(by1, y1[s]);
                    float xx2 = fminf(bx2, x2[s]);
                    float yy2 = fminf(by2, y2[s]);
                    float inter = fmaxf(xx2 - xx1, 0.f) * fmaxf(yy2 - yy1, 0.f);
                    float uni = (ar[s] - inter) + bar;
                    float iou = inter / uni;
                    if (!(iou <= NMS_T)) act[s] = 0;   // NaN suppresses
                }
            }
        }
    }
    #pragma unroll
    for (int s = 0; s < 4; s++) {
        int j = s * 64 + lane;
        if (j < M_TOP) kept[(size_t)row * M_TOP + j] = kf[s] ? sv[s] : 0.0f;
    }
}

// ---------------- Kernel E1: compact positive kept-scores per batch ----------------
__global__ __launch_bounds__(256) void gcompact_kernel(
        const float* __restrict__ kept, float* __restrict__ cmpval,
        int* __restrict__ cmpidx, int* __restrict__ pcnt, int M, int B) {
    int i = blockIdx.x * blockDim.x + threadIdx.x;
    if (i >= B * M) return;
    int b = i / M, fi = i % M;
    float val = kept[i];
    if (val > 0.0f) {
        int p = atomicAdd(&pcnt[b], 1);
        cmpval[(size_t)b * M + p] = val;
        cmpidx[(size_t)b * M + p] = fi;
    }
}

// ---------------- Kernel E2: top-200 of compacted positives, scatter to finsc --------
__global__ __launch_bounds__(256) void gtop_kernel(
        const float* __restrict__ cmpval, const int* __restrict__ cmpidx,
        const int* __restrict__ pcnt, float* __restrict__ finsc, int M) {
    int b = blockIdx.x;
    int tid = threadIdx.x;
    int P = pcnt[b];
    const float* cv = cmpval + (size_t)b * M;
    const int*   ci = cmpidx + (size_t)b * M;
    float* fo = finsc + (size_t)b * M;
    if (P <= M_TOP) {                      // all positives kept
        for (int i = tid; i < P; i += 256) fo[ci[i]] = cv[i];
        return;
    }
    __shared__ uint32_t hist[256];
    __shared__ uint32_t s_prefix, s_want;
    __shared__ int tiebuf[256];
    __shared__ uint32_t ntie;
    __shared__ int cutoff;
    if (tid == 0) { s_prefix = 0; s_want = M_TOP; }
    for (int pass = 0; pass < 4; pass++) {
        hist[tid] = 0;
        __syncthreads();
        uint32_t prefix = s_prefix;
        int shift = 24 - 8 * pass;
        for (int i = tid; i < P; i += 256) {
            uint32_t k = fkey(cv[i]);
            bool ok = (pass == 0) || ((k >> (shift + 8)) == (prefix >> (shift + 8)));
            if (ok) atomicAdd(&hist[(k >> shift) & 255u], 1u);
        }
        __syncthreads();
        if (tid == 0) {
            uint32_t want = s_want, cum = 0; int bin = 0;
            for (int bb = 255; bb >= 0; bb--) {
                if (cum + hist[bb] >= want) { bin = bb; break; }
                cum += hist[bb];
            }
            s_want = want - cum;
            s_prefix = prefix | ((uint32_t)bin << shift);
        }
        __syncthreads();
    }
    uint32_t kth = s_prefix, rfin = s_want;
    if (tid == 0) { ntie = 0; cutoff = -1; }
    __syncthreads();
    for (int i = tid; i < P; i += 256) {
        if (fkey(cv[i]) == kth) { uint32_t p = atomicAdd(&ntie, 1u); if (p < 256) tiebuf[p] = ci[i]; }
    }
    __syncthreads();
    uint32_t nt = min(ntie, 256u);
    if (tid < (int)nt) {
        int mine = tiebuf[tid];
        uint32_t rk = 0;
        for (uint32_t j = 0; j < nt; j++) if (tiebuf[j] < mine) rk++;
        if (rk == rfin - 1) cutoff = mine;
    }
    __syncthreads();
    int cut = cutoff;
    for (int i = tid; i < P; i += 256) {
        uint32_t k = fkey(cv[i]);
        if (k > kth || (k == kth && ci[i] <= cut)) fo[ci[i]] = cv[i];
    }
}

// ---------------- Kernel F: per-class stable sort + output ----------------
__global__ __launch_bounds__(256) void out_kernel(
        const float* __restrict__ finsc, const float* __restrict__ cand,
        float* __restrict__ out, int C, int Cm1) {
    int row = blockIdx.x;   // b*Cm1 + c
    int b = row / Cm1, c = row % Cm1;
    int tid = threadIdx.x;
    __shared__ float s[M_TOP];
    if (tid < M_TOP) s[tid] = finsc[(size_t)row * M_TOP + tid];
    __syncthreads();
    if (tid < M_TOP) {
        float mv = s[tid];
        uint32_t rk = 0;
        for (int j = 0; j < M_TOP; j++) {
            float jv = s[j];
            if (jv > mv || (jv == mv && j < tid)) rk++;
        }
        size_t obase = (((size_t)(b * C + c + 1)) * M_TOP + rk) * 5;
        out[obase] = mv;
        float4 bb;
        if (mv > 0.f) bb = ((const float4*)cand)[(size_t)row * M_TOP + tid];
        else { bb.x = 0.f; bb.y = 0.f; bb.z = 0.f; bb.w = 0.f; }
        out[obase + 1] = bb.x; out[obase + 2] = bb.y;
        out[obase + 3] = bb.z; out[obase + 4] = bb.w;
    }
}

extern "C" void kernel_launch(void* const* d_in, const int* in_sizes, int n_in,
                              void* d_out, int out_size, void* d_ws, size_t ws_size,
                              hipStream_t stream) {
    const float* loc  = (const float*)d_in[0];
    const float* conf = (const float*)d_in[1];
    const float* dbox = (const float*)d_in[2];
    int N   = in_sizes[2] / 4;
    int B   = in_sizes[0] / (4 * N);
    int C   = in_sizes[1] / (B * N);
    int Cm1 = C - 1;
    int M   = Cm1 * M_TOP;                 // 16000 per batch

    char* ws = (char*)d_ws;
    size_t off = 0;
    auto alloc = [&](size_t bytes) -> char* {
        char* p = ws + off;
        off = (off + bytes + 255) & ~(size_t)255;
        return p;
    };
    float* boxes  = (float*)alloc((size_t)B * N * 4 * sizeof(float));
    float* sc     = (float*)alloc((size_t)B * Cm1 * N * sizeof(float));
    float* tk_sc  = (float*)alloc((size_t)B * M * sizeof(float));
    float* cand   = (float*)alloc((size_t)B * M * 4 * sizeof(float));
    float* kept   = (float*)alloc((size_t)B * M * sizeof(float));
    // finsc + pcnt adjacent -> one memset covers both (finsc bytes are 256-aligned)
    float* finsc  = (float*)alloc((size_t)B * M * sizeof(float));
    int*   pcnt   = (int*)alloc((size_t)B * sizeof(int));
    float* cmpval = (float*)alloc((size_t)B * M * sizeof(float));
    int*   cmpidx = (int*)alloc((size_t)B * M * sizeof(int));

    int bn = B * N;
    decode_kernel<<<(bn + 255) / 256, 256, 0, stream>>>(loc, dbox, boxes, B, N);
    softmax_kernel<<<(bn + SM_ROWS - 1) / SM_ROWS, SM_ROWS, 0, stream>>>(conf, sc, B, N, C);
    topk_kernel<<<B * Cm1, TK_BS, 0, stream>>>(sc, boxes, tk_sc, cand, B, N, Cm1);
    nms_kernel<<<B * Cm1, 64, 0, stream>>>(tk_sc, cand, kept);
    hipMemsetAsync(finsc, 0, (size_t)B * M * sizeof(float) + 256, stream); // finsc + pcnt
    gcompact_kernel<<<(B * M + 255) / 256, 256, 0, stream>>>(kept, cmpval, cmpidx, pcnt, M, B);
    gtop_kernel<<<B, 256, 0, stream>>>(cmpval, cmpidx, pcnt, finsc, M);
    hipMemsetAsync(d_out, 0, (size_t)out_size * sizeof(float), stream);
    out_kernel<<<B * Cm1, 256, 0, stream>>>(finsc, cand, (float*)d_out, C, Cm1);
}

// Round 7
// 391.761 us; speedup vs baseline: 2.5642x; 2.5642x over previous
//
#include <hip/hip_runtime.h>
#include <stdint.h>

#define CONF_T 0.01f
#define NMS_T  0.45f
#define M_TOP  200
#define SM_ROWS 64    // rows per softmax block (64 threads); LDS 20.7 KB -> 7 blocks/CU
#define TK_BS  256    // topk block size
#define TCAP   4096   // topk tie-bin compaction capacity (LDS)

__device__ __forceinline__ uint32_t fkey(float f) {
    uint32_t u = __float_as_uint(f);
    return (u & 0x80000000u) ? ~u : (u | 0x80000000u);
}
__device__ __forceinline__ float fkey_inv(uint32_t k) {
    uint32_t u = (k & 0x80000000u) ? (k & 0x7FFFFFFFu) : ~k;
    return __uint_as_float(u);
}

// Parallel suffix-scan bin selection over nb bins (nb multiple of 256).
__device__ __forceinline__ void suffix_select(
        uint32_t* hist, uint32_t* part, int nb, uint32_t pref, int shift,
        uint32_t wantv, uint32_t* s_prefix, uint32_t* s_want) {
    int tid = threadIdx.x;
    int bpt = nb >> 8;
    int base = tid * bpt;
    uint32_t loc = 0;
    for (int j = 0; j < bpt; j++) loc += hist[base + j];
    part[tid] = loc;
    __syncthreads();
    for (int d = 1; d < 256; d <<= 1) {
        uint32_t y = (tid + d < 256) ? part[tid + d] : 0u;
        __syncthreads();
        part[tid] += y;
        __syncthreads();
    }
    uint32_t run = part[tid] - loc;
    for (int j = bpt - 1; j >= 0; j--) {
        uint32_t h = hist[base + j];
        uint32_t sfx = run + h;
        if (run < wantv && sfx >= wantv) {
            *s_prefix = pref | ((uint32_t)(base + j) << shift);
            *s_want   = wantv - run;
        }
        run = sfx;
    }
    __syncthreads();
}

// ---------------- Kernel A: decode boxes ----------------
__global__ __launch_bounds__(256) void decode_kernel(
        const float* __restrict__ loc, const float* __restrict__ dbox,
        float* __restrict__ boxes, int B, int N) {
    int i = blockIdx.x * blockDim.x + threadIdx.x;
    if (i >= B * N) return;
    int n = i % N;
    float4 l = ((const float4*)loc)[i];
    float4 d = ((const float4*)dbox)[n];
    float cx = d.x + (l.x * 0.1f) * d.z;
    float cy = d.y + (l.y * 0.1f) * d.w;
    float w  = d.z * expf(l.z * 0.2f);
    float h  = d.w * expf(l.w * 0.2f);
    float x1 = cx - w * 0.5f, y1 = cy - h * 0.5f;
    float x2 = x1 + w, y2 = y1 + h;
    float4 o;
    o.x = fminf(fmaxf(x1, 0.f), 1.f);
    o.y = fminf(fmaxf(y1, 0.f), 1.f);
    o.z = fminf(fmaxf(x2, 0.f), 1.f);
    o.w = fminf(fmaxf(y2, 0.f), 1.f);
    ((float4*)boxes)[i] = o;
}

// ---------------- Kernel B: softmax + transpose (64-row blocks) ----------------
__global__ __launch_bounds__(SM_ROWS) void softmax_kernel(
        const float* __restrict__ conf, float* __restrict__ sc,
        int B, int N, int C) {
    __shared__ float rows[SM_ROWS * 81];
    int tid = threadIdx.x;
    int BN = B * N;
    long long r0 = (long long)blockIdx.x * SM_ROWS;
    int nrows = BN - (int)r0; if (nrows > SM_ROWS) nrows = SM_ROWS;
    int totalf = nrows * 81;
    const float* g = conf + r0 * 81;
    int total4 = totalf >> 2;
    const float4* g4 = (const float4*)g;
    float4* l4 = (float4*)rows;
    for (int i = tid; i < total4; i += SM_ROWS) l4[i] = g4[i];
    for (int i = (total4 << 2) + tid; i < totalf; i += SM_ROWS) rows[i] = g[i];
    __syncthreads();
    if (tid < nrows) {
        float* p = rows + tid * 81;
        float m = p[0];
        for (int c = 1; c < 81; c++) m = fmaxf(m, p[c]);
        float s = 0.f;
        for (int c = 0; c < 81; c++) { float e = expf(p[c] - m); p[c] = e; s += e; }
        int r = (int)r0 + tid;
        int b = r / N, n = r % N;
        size_t base = ((size_t)b * (C - 1)) * N + n;
        for (int c = 1; c < 81; c++) {
            sc[base + (size_t)(c - 1) * N] = p[c] / s;
        }
    }
}

// ---------------- Kernel C: per-row exact top-200 (2 global sweeps + LDS select) ------
__global__ __launch_bounds__(TK_BS) void topk_kernel(
        const float* __restrict__ sc, const float* __restrict__ boxes,
        float* __restrict__ tk_sc, float* __restrict__ cand,
        int B, int N, int Cm1) {
    const uint32_t KEYN1 = 0x407FFFFFu;        // fkey(-1.0f)
    const uint32_t BIN_N1 = KEYN1 >> 21;       // 0x203
    __shared__ uint32_t hist[2048];
    __shared__ uint32_t part[256];
    __shared__ uint32_t tk[TCAP];              // tie-bin keys
    __shared__ int      tix[TCAP];             // tie-bin indices
    __shared__ uint32_t s_prefix, s_want;
    __shared__ uint32_t ngt, ntie, tcnt;
    __shared__ float    e_val[256];
    __shared__ int      e_idx[256];
    __shared__ int      tiebuf[256];

    int row = blockIdx.x;                      // b*Cm1 + c
    int b = row / Cm1;
    int tid = threadIdx.x;
    const float* v = sc + (size_t)row * N;
    const float4* v4 = (const float4*)v;
    int n4 = N >> 2;

    // ---- phase 1: 2048-bin histogram of top-11 key bits (global sweep 1) ----
    for (int i = tid; i < 2048; i += TK_BS) hist[i] = 0;
    if (tid == 0) { s_prefix = 0; s_want = M_TOP; }
    __syncthreads();
    for (int i = tid; i < n4; i += TK_BS) {
        float4 f = v4[i];
        atomicAdd(&hist[fkey(f.x > CONF_T ? f.x : -1.0f) >> 21], 1u);
        atomicAdd(&hist[fkey(f.y > CONF_T ? f.y : -1.0f) >> 21], 1u);
        atomicAdd(&hist[fkey(f.z > CONF_T ? f.z : -1.0f) >> 21], 1u);
        atomicAdd(&hist[fkey(f.w > CONF_T ? f.w : -1.0f) >> 21], 1u);
    }
    for (int i = (n4 << 2) + tid; i < N; i += TK_BS)
        atomicAdd(&hist[fkey(v[i] > CONF_T ? v[i] : -1.0f) >> 21], 1u);
    __syncthreads();
    suffix_select(hist, part, 2048, 0u, 21, M_TOP, &s_prefix, &s_want);
    uint32_t b0 = s_prefix >> 21;
    uint32_t want1 = s_want;

    // ---- phase 2: compaction (global sweep 2) ----
    if (tid < 256) { e_val[tid] = -1.0f; e_idx[tid] = tid; }
    if (tid == 0) { ngt = 0; ntie = 0; tcnt = 0; }
    __syncthreads();
    bool collect_ties = (b0 != BIN_N1);
    for (int i = tid; i < n4; i += TK_BS) {
        float4 f = v4[i];
        float mv[4] = { f.x > CONF_T ? f.x : -1.0f, f.y > CONF_T ? f.y : -1.0f,
                        f.z > CONF_T ? f.z : -1.0f, f.w > CONF_T ? f.w : -1.0f };
        #pragma unroll
        for (int j = 0; j < 4; j++) {
            uint32_t k = fkey(mv[j]);
            uint32_t bin = k >> 21;
            int idx = 4 * i + j;
            if (bin > b0) {
                uint32_t p = atomicAdd(&ngt, 1u);   // < 200 guaranteed
                if (p < 256) { e_val[p] = mv[j]; e_idx[p] = idx; }
            } else if (bin == b0 && collect_ties) {
                uint32_t p = atomicAdd(&tcnt, 1u);
                if (p < TCAP) { tk[p] = k; tix[p] = idx; }
            }
        }
    }
    for (int i = (n4 << 2) + tid; i < N; i += TK_BS) {
        float f = v[i];
        float mv = f > CONF_T ? f : -1.0f;
        uint32_t k = fkey(mv);
        uint32_t bin = k >> 21;
        if (bin > b0) {
            uint32_t p = atomicAdd(&ngt, 1u);
            if (p < 256) { e_val[p] = mv; e_idx[p] = i; }
        } else if (bin == b0 && collect_ties) {
            uint32_t p = atomicAdd(&tcnt, 1u);
            if (p < TCAP) { tk[p] = k; tix[p] = i; }
        }
    }
    __syncthreads();

    uint32_t kth = KEYN1, rfin = 0;
    if (collect_ties && tcnt <= TCAP) {
        // ---- phase 3: 2-level radix select entirely from the LDS tie buffer ----
        int T = (int)tcnt;
        for (int i = tid; i < 2048; i += TK_BS) hist[i] = 0;
        __syncthreads();
        for (int i = tid; i < T; i += TK_BS) atomicAdd(&hist[(tk[i] >> 10) & 2047u], 1u);
        __syncthreads();
        suffix_select(hist, part, 2048, b0 << 21, 10, want1, &s_prefix, &s_want);
        uint32_t pre2 = s_prefix; uint32_t want2 = s_want;
        uint32_t b1 = (pre2 >> 10) & 2047u;
        for (int i = tid; i < 1024; i += TK_BS) hist[i] = 0;
        __syncthreads();
        for (int i = tid; i < T; i += TK_BS)
            if (((tk[i] >> 10) & 2047u) == b1) atomicAdd(&hist[tk[i] & 1023u], 1u);
        __syncthreads();
        suffix_select(hist, part, 1024, pre2, 0, want2, &s_prefix, &s_want);
        kth = s_prefix; rfin = s_want;
        for (int i = tid; i < T; i += TK_BS) {
            uint32_t k = tk[i];
            if (k > kth) {
                uint32_t p = atomicAdd(&ngt, 1u);
                if (p < 256) { e_val[p] = fkey_inv(k); e_idx[p] = tix[i]; }
            } else if (k == kth) {
                uint32_t p = atomicAdd(&ntie, 1u);
                if (p < 256) tiebuf[p] = tix[i];
            }
        }
        __syncthreads();
    } else if (collect_ties) {
        // ---- overflow fallback: finish radix with global sweeps (rare) ----
        const int shifts[2] = {10, 0};
        const int nbins_[2] = {2048, 1024};
        for (int lev = 0; lev < 2; lev++) {
            int shift = shifts[lev];
            int nb = nbins_[lev];
            uint32_t bmask = (uint32_t)nb - 1u;
            uint32_t pref = s_prefix, wantv = s_want;
            uint32_t pmask = 0xFFFFFFFFu << (shift + ((nb == 2048) ? 11 : 10));
            for (int i = tid; i < nb; i += TK_BS) hist[i] = 0;
            __syncthreads();
            for (int i = tid; i < N; i += TK_BS) {
                float f = v[i];
                uint32_t k = fkey(f > CONF_T ? f : -1.0f);
                if ((k & pmask) == pref) atomicAdd(&hist[(k >> shift) & bmask], 1u);
            }
            __syncthreads();
            suffix_select(hist, part, nb, pref, shift, wantv, &s_prefix, &s_want);
        }
        kth = s_prefix; rfin = s_want;
        for (int i = tid; i < N; i += TK_BS) {
            float f = v[i];
            float mv = f > CONF_T ? f : -1.0f;
            uint32_t k = fkey(mv);
            if ((k >> 21) == b0) {
                if (k > kth) {
                    uint32_t p = atomicAdd(&ngt, 1u);
                    if (p < 256) { e_val[p] = mv; e_idx[p] = i; }
                } else if (k == kth) {
                    uint32_t p = atomicAdd(&ntie, 1u);
                    if (p < 256) tiebuf[p] = i;
                }
            }
        }
        __syncthreads();
    }

    uint32_t gcount = min(ngt, (uint32_t)M_TOP);
    if (collect_ties) {
        uint32_t nt = min(ntie, 256u);
        if (tid < (int)nt) {
            int mine = tiebuf[tid];
            uint32_t rk = 0;
            for (uint32_t j = 0; j < nt; j++) if (tiebuf[j] < mine) rk++;
            if (rk < rfin) {
                uint32_t slot = gcount + rk;
                if (slot < M_TOP) { e_val[slot] = fkey_inv(kth); e_idx[slot] = mine; }
            }
        }
    }
    __syncthreads();
    // final stable ordering: (key desc, idx asc) via counting rank
    if (tid < M_TOP) {
        float mv = e_val[tid]; int mi = e_idx[tid];
        uint32_t mk = fkey(mv);
        uint32_t rk = 0;
        for (int j = 0; j < M_TOP; j++) {
            uint32_t jk = fkey(e_val[j]); int ji = e_idx[j];
            if (jk > mk || (jk == mk && ji < mi)) rk++;
        }
        size_t base = (size_t)row * M_TOP + rk;
        tk_sc[base] = mv;
        float4 bb = ((const float4*)boxes)[(size_t)b * N + mi];
        ((float4*)cand)[base] = bb;
    }
}

// ---------------- Kernel D: greedy NMS + fused compaction, one wave per row ----------
// After NMS, the wave counts kept boxes via ballot, reserves a contiguous
// range in (cmpval,cmpidx) with ONE global atomic per row, and writes
// (score, flat-idx) pairs. Compaction order is irrelevant downstream.
__global__ __launch_bounds__(64) void nms_kernel(
        const float* __restrict__ tk_sc, const float* __restrict__ cand,
        float* __restrict__ cmpval, int* __restrict__ cmpidx,
        int* __restrict__ pcnt, int M, int Cm1) {
    int row = blockIdx.x;
    int b = row / Cm1, c = row % Cm1;
    int lane = threadIdx.x;
    float x1[4], y1[4], x2[4], y2[4], ar[4], sv[4];
    int act[4], kf[4];
    #pragma unroll
    for (int s = 0; s < 4; s++) {
        int j = s * 64 + lane;
        if (j < M_TOP) {
            size_t base = (size_t)row * M_TOP + j;
            float4 bb = ((const float4*)cand)[base];
            x1[s] = bb.x; y1[s] = bb.y; x2[s] = bb.z; y2[s] = bb.w;
            ar[s] = (bb.z - bb.x) * (bb.w - bb.y);
            sv[s] = tk_sc[base];
        } else { x1[s] = 0.f; y1[s] = 0.f; x2[s] = 0.f; y2[s] = 0.f; ar[s] = 0.f; sv[s] = -1.0f; }
        act[s] = (sv[s] > CONF_T) ? 1 : 0;
        kf[s] = 0;
    }
    #pragma unroll
    for (int si = 0; si < 4; si++) {
        int lim = M_TOP - si * 64; if (lim > 64) lim = 64;
        for (int li = 0; li < lim; li++) {
            int a = __shfl(act[si], li);
            if (a) {
                if (lane == li) kf[si] = 1;
                float bx1 = __shfl(x1[si], li);
                float by1 = __shfl(y1[si], li);
                float bx2 = __shfl(x2[si], li);
                float by2 = __shfl(y2[si], li);
                float bar = __shfl(ar[si], li);
                #pragma unroll
                for (int s = 0; s < 4; s++) {
                    float xx1 = fmaxf(bx1, x1[s]);
                    float yy1 = fmaxf(by1, y1[s]);
                    float xx2 = fminf(bx2, x2[s]);
                    float yy2 = fminf(by2, y2[s]);
                    float inter = fmaxf(xx2 - xx1, 0.f) * fmaxf(yy2 - yy1, 0.f);
                    float uni = (ar[s] - inter) + bar;
                    float iou = inter / uni;
                    if (!(iou <= NMS_T)) act[s] = 0;   // NaN suppresses
                }
            }
        }
    }
    // fused compaction: ballot-prefix positions, one atomic per row
    unsigned long long ball[4];
    int total = 0;
    #pragma unroll
    for (int s = 0; s < 4; s++) { ball[s] = __ballot(kf[s] != 0); total += (int)__popcll(ball[s]); }
    int base = 0;
    if (lane == 0 && total > 0) base = atomicAdd(&pcnt[b], total);
    base = __shfl(base, 0);
    unsigned long long lower = (lane == 0) ? 0ull : (~0ull >> (64 - lane));
    int off = base;
    #pragma unroll
    for (int s = 0; s < 4; s++) {
        if (kf[s]) {
            int pos = off + (int)__popcll(ball[s] & lower);
            cmpval[(size_t)b * M + pos] = sv[s];
            cmpidx[(size_t)b * M + pos] = c * M_TOP + s * 64 + lane;
        }
        off += (int)__popcll(ball[s]);
    }
}

// ---------------- Kernel E: top-200 of compacted positives, scatter to finsc --------
__global__ __launch_bounds__(256) void gtop_kernel(
        const float* __restrict__ cmpval, const int* __restrict__ cmpidx,
        const int* __restrict__ pcnt, float* __restrict__ finsc, int M) {
    int b = blockIdx.x;
    int tid = threadIdx.x;
    int P = pcnt[b];
    const float* cv = cmpval + (size_t)b * M;
    const int*   ci = cmpidx + (size_t)b * M;
    float* fo = finsc + (size_t)b * M;
    if (P <= M_TOP) {                      // all positives kept
        for (int i = tid; i < P; i += 256) fo[ci[i]] = cv[i];
        return;
    }
    __shared__ uint32_t hist[256];
    __shared__ uint32_t s_prefix, s_want;
    __shared__ int tiebuf[256];
    __shared__ uint32_t ntie;
    __shared__ int cutoff;
    if (tid == 0) { s_prefix = 0; s_want = M_TOP; }
    for (int pass = 0; pass < 4; pass++) {
        hist[tid] = 0;
        __syncthreads();
        uint32_t prefix = s_prefix;
        int shift = 24 - 8 * pass;
        for (int i = tid; i < P; i += 256) {
            uint32_t k = fkey(cv[i]);
            bool ok = (pass == 0) || ((k >> (shift + 8)) == (prefix >> (shift + 8)));
            if (ok) atomicAdd(&hist[(k >> shift) & 255u], 1u);
        }
        __syncthreads();
        if (tid == 0) {
            uint32_t want = s_want, cum = 0; int bin = 0;
            for (int bb = 255; bb >= 0; bb--) {
                if (cum + hist[bb] >= want) { bin = bb; break; }
                cum += hist[bb];
            }
            s_want = want - cum;
            s_prefix = prefix | ((uint32_t)bin << shift);
        }
        __syncthreads();
    }
    uint32_t kth = s_prefix, rfin = s_want;
    if (tid == 0) { ntie = 0; cutoff = -1; }
    __syncthreads();
    for (int i = tid; i < P; i += 256) {
        if (fkey(cv[i]) == kth) { uint32_t p = atomicAdd(&ntie, 1u); if (p < 256) tiebuf[p] = ci[i]; }
    }
    __syncthreads();
    uint32_t nt = min(ntie, 256u);
    if (tid < (int)nt) {
        int mine = tiebuf[tid];
        uint32_t rk = 0;
        for (uint32_t j = 0; j < nt; j++) if (tiebuf[j] < mine) rk++;
        if (rk == rfin - 1) cutoff = mine;
    }
    __syncthreads();
    int cut = cutoff;
    for (int i = tid; i < P; i += 256) {
        uint32_t k = fkey(cv[i]);
        if (k > kth || (k == kth && ci[i] <= cut)) fo[ci[i]] = cv[i];
    }
}

// ---------------- Kernel F: per-class stable sort + output ----------------
__global__ __launch_bounds__(256) void out_kernel(
        const float* __restrict__ finsc, const float* __restrict__ cand,
        float* __restrict__ out, int C, int Cm1) {
    int row = blockIdx.x;   // b*Cm1 + c
    int b = row / Cm1, c = row % Cm1;
    int tid = threadIdx.x;
    __shared__ float s[M_TOP];
    if (tid < M_TOP) s[tid] = finsc[(size_t)row * M_TOP + tid];
    __syncthreads();
    if (tid < M_TOP) {
        float mv = s[tid];
        uint32_t rk = 0;
        for (int j = 0; j < M_TOP; j++) {
            float jv = s[j];
            if (jv > mv || (jv == mv && j < tid)) rk++;
        }
        size_t obase = (((size_t)(b * C + c + 1)) * M_TOP + rk) * 5;
        out[obase] = mv;
        float4 bb;
        if (mv > 0.f) bb = ((const float4*)cand)[(size_t)row * M_TOP + tid];
        else { bb.x = 0.f; bb.y = 0.f; bb.z = 0.f; bb.w = 0.f; }
        out[obase + 1] = bb.x; out[obase + 2] = bb.y;
        out[obase + 3] = bb.z; out[obase + 4] = bb.w;
    }
}

extern "C" void kernel_launch(void* const* d_in, const int* in_sizes, int n_in,
                              void* d_out, int out_size, void* d_ws, size_t ws_size,
                              hipStream_t stream) {
    const float* loc  = (const float*)d_in[0];
    const float* conf = (const float*)d_in[1];
    const float* dbox = (const float*)d_in[2];
    int N   = in_sizes[2] / 4;
    int B   = in_sizes[0] / (4 * N);
    int C   = in_sizes[1] / (B * N);
    int Cm1 = C - 1;
    int M   = Cm1 * M_TOP;                 // 16000 per batch

    char* ws = (char*)d_ws;
    size_t off = 0;
    auto alloc = [&](size_t bytes) -> char* {
        char* p = ws + off;
        off = (off + bytes + 255) & ~(size_t)255;
        return p;
    };
    float* boxes  = (float*)alloc((size_t)B * N * 4 * sizeof(float));
    float* sc     = (float*)alloc((size_t)B * Cm1 * N * sizeof(float));
    float* tk_sc  = (float*)alloc((size_t)B * M * sizeof(float));
    float* cand   = (float*)alloc((size_t)B * M * 4 * sizeof(float));
    // finsc + pcnt adjacent -> one memset covers both (finsc bytes are 256-aligned)
    float* finsc  = (float*)alloc((size_t)B * M * sizeof(float));
    int*   pcnt   = (int*)alloc((size_t)B * sizeof(int));
    float* cmpval = (float*)alloc((size_t)B * M * sizeof(float));
    int*   cmpidx = (int*)alloc((size_t)B * M * sizeof(int));

    int bn = B * N;
    decode_kernel<<<(bn + 255) / 256, 256, 0, stream>>>(loc, dbox, boxes, B, N);
    softmax_kernel<<<(bn + SM_ROWS - 1) / SM_ROWS, SM_ROWS, 0, stream>>>(conf, sc, B, N, C);
    topk_kernel<<<B * Cm1, TK_BS, 0, stream>>>(sc, boxes, tk_sc, cand, B, N, Cm1);
    hipMemsetAsync(finsc, 0, (size_t)B * M * sizeof(float) + 256, stream); // finsc + pcnt
    nms_kernel<<<B * Cm1, 64, 0, stream>>>(tk_sc, cand, cmpval, cmpidx, pcnt, M, Cm1);
    gtop_kernel<<<B, 256, 0, stream>>>(cmpval, cmpidx, pcnt, finsc, M);
    hipMemsetAsync(d_out, 0, (size_t)out_size * sizeof(float), stream);
    out_kernel<<<B * Cm1, 256, 0, stream>>>(finsc, cand, (float*)d_out, C, Cm1);
}

// Round 8
// 351.194 us; speedup vs baseline: 2.8604x; 1.1155x over previous
//
#include <hip/hip_runtime.h>
#include <stdint.h>

#define CONF_T 0.01f
#define NMS_T  0.45f
#define M_TOP  200
#define SM_ROWS 64    // rows per softmax block (64 threads); LDS 20.7 KB -> 7 blocks/CU
#define TK_BS  256    // topk block size
#define TCAP   4096   // topk bracket buffer capacity (LDS)

__device__ __forceinline__ uint32_t fkey(float f) {
    uint32_t u = __float_as_uint(f);
    return (u & 0x80000000u) ? ~u : (u | 0x80000000u);
}
__device__ __forceinline__ float fkey_inv(uint32_t k) {
    uint32_t u = (k & 0x80000000u) ? (k & 0x7FFFFFFFu) : ~k;
    return __uint_as_float(u);
}

// Parallel suffix-scan bin selection over nb bins (nb multiple of 256).
// Finds max bin x with suffix_sum(x) >= want (suffix_sum decreasing in x);
// writes pref|x<<shift and residual want. All 256 threads; barriers inside.
__device__ __forceinline__ void suffix_select(
        uint32_t* hist, uint32_t* part, int nb, uint32_t pref, int shift,
        uint32_t wantv, uint32_t* s_prefix, uint32_t* s_want) {
    int tid = threadIdx.x;
    int bpt = nb >> 8;
    int base = tid * bpt;
    uint32_t loc = 0;
    for (int j = 0; j < bpt; j++) loc += hist[base + j];
    part[tid] = loc;
    __syncthreads();
    for (int d = 1; d < 256; d <<= 1) {
        uint32_t y = (tid + d < 256) ? part[tid + d] : 0u;
        __syncthreads();
        part[tid] += y;
        __syncthreads();
    }
    uint32_t run = part[tid] - loc;
    for (int j = bpt - 1; j >= 0; j--) {
        uint32_t h = hist[base + j];
        uint32_t sfx = run + h;
        if (run < wantv && sfx >= wantv) {
            *s_prefix = pref | ((uint32_t)(base + j) << shift);
            *s_want   = wantv - run;
        }
        run = sfx;
    }
    __syncthreads();
}

// ---------------- Kernel A: decode boxes ----------------
__global__ __launch_bounds__(256) void decode_kernel(
        const float* __restrict__ loc, const float* __restrict__ dbox,
        float* __restrict__ boxes, int B, int N) {
    int i = blockIdx.x * blockDim.x + threadIdx.x;
    if (i >= B * N) return;
    int n = i % N;
    float4 l = ((const float4*)loc)[i];
    float4 d = ((const float4*)dbox)[n];
    float cx = d.x + (l.x * 0.1f) * d.z;
    float cy = d.y + (l.y * 0.1f) * d.w;
    float w  = d.z * expf(l.z * 0.2f);
    float h  = d.w * expf(l.w * 0.2f);
    float x1 = cx - w * 0.5f, y1 = cy - h * 0.5f;
    float x2 = x1 + w, y2 = y1 + h;
    float4 o;
    o.x = fminf(fmaxf(x1, 0.f), 1.f);
    o.y = fminf(fmaxf(y1, 0.f), 1.f);
    o.z = fminf(fmaxf(x2, 0.f), 1.f);
    o.w = fminf(fmaxf(y2, 0.f), 1.f);
    ((float4*)boxes)[i] = o;
}

// ---------------- Kernel B: softmax + transpose (64-row blocks) ----------------
__global__ __launch_bounds__(SM_ROWS) void softmax_kernel(
        const float* __restrict__ conf, float* __restrict__ sc,
        int B, int N, int C) {
    __shared__ float rows[SM_ROWS * 81];
    int tid = threadIdx.x;
    int BN = B * N;
    long long r0 = (long long)blockIdx.x * SM_ROWS;
    int nrows = BN - (int)r0; if (nrows > SM_ROWS) nrows = SM_ROWS;
    int totalf = nrows * 81;
    const float* g = conf + r0 * 81;
    int total4 = totalf >> 2;
    const float4* g4 = (const float4*)g;
    float4* l4 = (float4*)rows;
    for (int i = tid; i < total4; i += SM_ROWS) l4[i] = g4[i];
    for (int i = (total4 << 2) + tid; i < totalf; i += SM_ROWS) rows[i] = g[i];
    __syncthreads();
    if (tid < nrows) {
        float* p = rows + tid * 81;
        float m = p[0];
        for (int c = 1; c < 81; c++) m = fmaxf(m, p[c]);
        float s = 0.f;
        for (int c = 0; c < 81; c++) { float e = expf(p[c] - m); p[c] = e; s += e; }
        int r = (int)r0 + tid;
        int b = r / N, n = r % N;
        size_t base = ((size_t)b * (C - 1)) * N + n;
        for (int c = 1; c < 81; c++) {
            sc[base + (size_t)(c - 1) * N] = p[c] / s;
        }
    }
}

// ---------------- Kernel C: per-row exact top-200 (sample bracket + 1 sweep) ---------
// Sample 2048 strided elements -> pick bracket keys (lo,hi) from sample
// suffix-ranks 25 / 3. One full sweep: elements > hi go straight to the
// result table (count G <= 200 whp), elements in (lo,hi] go to an LDS buffer
// (count T ~ few hundred); ~98% of elements touch no LDS. Exact 3-level
// radix select over the buffer finds the k-th key. Bracket validity
// (G<=200, T<=TCAP, G+T>=200) is verified exactly; on violation the old
// 2-sweep histogram path runs -> correctness never depends on the sample.
__global__ __launch_bounds__(TK_BS) void topk_kernel(
        const float* __restrict__ sc, const float* __restrict__ boxes,
        float* __restrict__ tk_sc, float* __restrict__ cand,
        int B, int N, int Cm1) {
    const uint32_t KEYN1 = 0x407FFFFFu;        // fkey(-1.0f)
    const uint32_t BIN_N1 = KEYN1 >> 21;       // 0x203
    __shared__ uint32_t hist[2048];
    __shared__ uint32_t part[256];
    __shared__ uint32_t tk[TCAP];              // bracket keys (sample keys reuse [0..2047])
    __shared__ int      tix[TCAP];             // bracket indices
    __shared__ uint32_t s_prefix, s_want;
    __shared__ uint32_t ngt, ntie, tcnt;
    __shared__ float    e_val[256];
    __shared__ int      e_idx[256];
    __shared__ int      tiebuf[256];

    int row = blockIdx.x;                      // b*Cm1 + c
    int b = row / Cm1;
    int tid = threadIdx.x;
    const float* v = sc + (size_t)row * N;
    const float4* v4 = (const float4*)v;
    int n4 = N >> 2;

    // ---- sample phase ----
    bool sampled = (N >= 2048) && ((N & 7) == 0);
    uint32_t lo_key = 0xFFFFFFFFu, hi_key = 0xFFFFFFFFu;
    if (sampled) {
        int stride = N >> 3;
        for (int s = 0; s < 8; s++) {
            float f = v[s * stride + tid];
            tk[s * 256 + tid] = fkey(f > CONF_T ? f : -1.0f);
        }
        for (int i = tid; i < 2048; i += TK_BS) hist[i] = 0;
        __syncthreads();
        for (int i = tid; i < 2048; i += TK_BS) atomicAdd(&hist[tk[i] >> 21], 1u);
        __syncthreads();
        suffix_select(hist, part, 2048, 0u, 21, 3u, &s_prefix, &s_want);
        uint32_t h = s_prefix >> 21;
        suffix_select(hist, part, 2048, 0u, 21, 25u, &s_prefix, &s_want);
        uint32_t l = s_prefix >> 21;
        hi_key = ((h + 1) << 21) - 1u;         // h=2047 wraps to 0xFFFFFFFF (G=0)
        lo_key = (l << 21) - 1u;
        sampled = (l > BIN_N1);                // bracket must sit above the -1 bin
    }

    // ---- init collectors ----
    e_val[tid] = -1.0f; e_idx[tid] = tid;
    if (tid == 0) { ngt = 0; ntie = 0; tcnt = 0; }
    __syncthreads();

    bool ok = false;
    uint32_t G = 0, T = 0;
    if (sampled) {
        // ---- the one full sweep ----
        for (int i = tid; i < n4; i += TK_BS) {
            float4 f = v4[i];
            float mv[4] = { f.x > CONF_T ? f.x : -1.0f, f.y > CONF_T ? f.y : -1.0f,
                            f.z > CONF_T ? f.z : -1.0f, f.w > CONF_T ? f.w : -1.0f };
            #pragma unroll
            for (int j = 0; j < 4; j++) {
                uint32_t k = fkey(mv[j]);
                if (k > lo_key) {
                    int idx = 4 * i + j;
                    if (k > hi_key) {
                        uint32_t p = atomicAdd(&ngt, 1u);
                        if (p < 256) { e_val[p] = mv[j]; e_idx[p] = idx; }
                    } else {
                        uint32_t p = atomicAdd(&tcnt, 1u);
                        if (p < TCAP) { tk[p] = k; tix[p] = idx; }
                    }
                }
            }
        }
        for (int i = (n4 << 2) + tid; i < N; i += TK_BS) {
            float f = v[i];
            float mv = f > CONF_T ? f : -1.0f;
            uint32_t k = fkey(mv);
            if (k > lo_key) {
                if (k > hi_key) {
                    uint32_t p = atomicAdd(&ngt, 1u);
                    if (p < 256) { e_val[p] = mv; e_idx[p] = i; }
                } else {
                    uint32_t p = atomicAdd(&tcnt, 1u);
                    if (p < TCAP) { tk[p] = k; tix[p] = i; }
                }
            }
        }
        __syncthreads();
        G = ngt; T = tcnt;
        ok = (G <= (uint32_t)M_TOP) && (T <= (uint32_t)TCAP) &&
             (G + T >= (uint32_t)M_TOP);
    }

    uint32_t kth = KEYN1, rfin = 0;
    if (ok) {
        uint32_t want_t = (uint32_t)M_TOP - G;
        if (want_t > 0) {
            // exact 3-level radix select over the LDS bracket buffer
            for (int i = tid; i < 2048; i += TK_BS) hist[i] = 0;
            __syncthreads();
            for (int i = tid; i < (int)T; i += TK_BS) atomicAdd(&hist[tk[i] >> 21], 1u);
            __syncthreads();
            suffix_select(hist, part, 2048, 0u, 21, want_t, &s_prefix, &s_want);
            uint32_t pre0 = s_prefix, w0 = s_want;
            uint32_t bb0 = pre0 >> 21;
            for (int i = tid; i < 2048; i += TK_BS) hist[i] = 0;
            __syncthreads();
            for (int i = tid; i < (int)T; i += TK_BS)
                if ((tk[i] >> 21) == bb0) atomicAdd(&hist[(tk[i] >> 10) & 2047u], 1u);
            __syncthreads();
            suffix_select(hist, part, 2048, pre0, 10, w0, &s_prefix, &s_want);
            uint32_t pre1 = s_prefix, w1 = s_want;
            for (int i = tid; i < 1024; i += TK_BS) hist[i] = 0;
            __syncthreads();
            for (int i = tid; i < (int)T; i += TK_BS)
                if ((tk[i] >> 10) == (pre1 >> 10)) atomicAdd(&hist[tk[i] & 1023u], 1u);
            __syncthreads();
            suffix_select(hist, part, 1024, pre1, 0, w1, &s_prefix, &s_want);
            kth = s_prefix; rfin = s_want;
            for (int i = tid; i < (int)T; i += TK_BS) {
                uint32_t k = tk[i];
                if (k > kth) {
                    uint32_t p = atomicAdd(&ngt, 1u);
                    if (p < 256) { e_val[p] = fkey_inv(k); e_idx[p] = tix[i]; }
                } else if (k == kth) {
                    uint32_t p = atomicAdd(&ntie, 1u);
                    if (p < 256) tiebuf[p] = tix[i];
                }
            }
            __syncthreads();
        }
    } else {
        // ---- fallback: exact 2-sweep histogram path (R7) ----
        e_val[tid] = -1.0f; e_idx[tid] = tid;
        if (tid == 0) { ngt = 0; ntie = 0; tcnt = 0; }
        for (int i = tid; i < 2048; i += TK_BS) hist[i] = 0;
        __syncthreads();
        for (int i = tid; i < n4; i += TK_BS) {
            float4 f = v4[i];
            atomicAdd(&hist[fkey(f.x > CONF_T ? f.x : -1.0f) >> 21], 1u);
            atomicAdd(&hist[fkey(f.y > CONF_T ? f.y : -1.0f) >> 21], 1u);
            atomicAdd(&hist[fkey(f.z > CONF_T ? f.z : -1.0f) >> 21], 1u);
            atomicAdd(&hist[fkey(f.w > CONF_T ? f.w : -1.0f) >> 21], 1u);
        }
        for (int i = (n4 << 2) + tid; i < N; i += TK_BS)
            atomicAdd(&hist[fkey(v[i] > CONF_T ? v[i] : -1.0f) >> 21], 1u);
        __syncthreads();
        suffix_select(hist, part, 2048, 0u, 21, M_TOP, &s_prefix, &s_want);
        uint32_t b0 = s_prefix >> 21;
        uint32_t want1 = s_want;
        bool collect_ties = (b0 != BIN_N1);
        for (int i = tid; i < N; i += TK_BS) {
            float f = v[i];
            float mv = f > CONF_T ? f : -1.0f;
            uint32_t k = fkey(mv);
            uint32_t bin = k >> 21;
            if (bin > b0) {
                uint32_t p = atomicAdd(&ngt, 1u);
                if (p < 256) { e_val[p] = mv; e_idx[p] = i; }
            } else if (bin == b0 && collect_ties) {
                uint32_t p = atomicAdd(&tcnt, 1u);
                if (p < TCAP) { tk[p] = k; tix[p] = i; }
            }
        }
        __syncthreads();
        if (collect_ties && tcnt <= TCAP) {
            int Tl = (int)tcnt;
            for (int i = tid; i < 2048; i += TK_BS) hist[i] = 0;
            __syncthreads();
            for (int i = tid; i < Tl; i += TK_BS) atomicAdd(&hist[(tk[i] >> 10) & 2047u], 1u);
            __syncthreads();
            suffix_select(hist, part, 2048, b0 << 21, 10, want1, &s_prefix, &s_want);
            uint32_t pre2 = s_prefix; uint32_t want2 = s_want;
            uint32_t b1 = (pre2 >> 10) & 2047u;
            for (int i = tid; i < 1024; i += TK_BS) hist[i] = 0;
            __syncthreads();
            for (int i = tid; i < Tl; i += TK_BS)
                if (((tk[i] >> 10) & 2047u) == b1) atomicAdd(&hist[tk[i] & 1023u], 1u);
            __syncthreads();
            suffix_select(hist, part, 1024, pre2, 0, want2, &s_prefix, &s_want);
            kth = s_prefix; rfin = s_want;
            for (int i = tid; i < Tl; i += TK_BS) {
                uint32_t k = tk[i];
                if (k > kth) {
                    uint32_t p = atomicAdd(&ngt, 1u);
                    if (p < 256) { e_val[p] = fkey_inv(k); e_idx[p] = tix[i]; }
                } else if (k == kth) {
                    uint32_t p = atomicAdd(&ntie, 1u);
                    if (p < 256) tiebuf[p] = tix[i];
                }
            }
            __syncthreads();
        } else if (collect_ties) {
            const int shifts[2] = {10, 0};
            const int nbins_[2] = {2048, 1024};
            if (tid == 0) { s_prefix = b0 << 21; s_want = want1; }
            __syncthreads();
            for (int lev = 0; lev < 2; lev++) {
                int shift = shifts[lev];
                int nb = nbins_[lev];
                uint32_t bmask = (uint32_t)nb - 1u;
                uint32_t pref = s_prefix, wantv = s_want;
                uint32_t pmask = 0xFFFFFFFFu << (shift + ((nb == 2048) ? 11 : 10));
                for (int i = tid; i < nb; i += TK_BS) hist[i] = 0;
                __syncthreads();
                for (int i = tid; i < N; i += TK_BS) {
                    float f = v[i];
                    uint32_t k = fkey(f > CONF_T ? f : -1.0f);
                    if ((k & pmask) == (pref & pmask)) atomicAdd(&hist[(k >> shift) & bmask], 1u);
                }
                __syncthreads();
                suffix_select(hist, part, nb, pref, shift, wantv, &s_prefix, &s_want);
            }
            kth = s_prefix; rfin = s_want;
            for (int i = tid; i < N; i += TK_BS) {
                float f = v[i];
                float mv = f > CONF_T ? f : -1.0f;
                uint32_t k = fkey(mv);
                if ((k >> 21) == b0) {
                    if (k > kth) {
                        uint32_t p = atomicAdd(&ngt, 1u);
                        if (p < 256) { e_val[p] = mv; e_idx[p] = i; }
                    } else if (k == kth) {
                        uint32_t p = atomicAdd(&ntie, 1u);
                        if (p < 256) tiebuf[p] = i;
                    }
                }
            }
            __syncthreads();
        }
    }

    // ---- shared epilogue: insert kth-valued ties, then rank-order write ----
    uint32_t gcount = min(ngt, (uint32_t)M_TOP);
    uint32_t nt = min(ntie, 256u);
    if (tid < (int)nt) {
        int mine = tiebuf[tid];
        uint32_t rk = 0;
        for (uint32_t j = 0; j < nt; j++) if (tiebuf[j] < mine) rk++;
        if (rk < rfin) {
            uint32_t slot = gcount + rk;
            if (slot < M_TOP) { e_val[slot] = fkey_inv(kth); e_idx[slot] = mine; }
        }
    }
    __syncthreads();
    if (tid < M_TOP) {
        float mv = e_val[tid]; int mi = e_idx[tid];
        uint32_t mk = fkey(mv);
        uint32_t rk = 0;
        for (int j = 0; j < M_TOP; j++) {
            uint32_t jk = fkey(e_val[j]); int ji = e_idx[j];
            if (jk > mk || (jk == mk && ji < mi)) rk++;
        }
        size_t base = (size_t)row * M_TOP + rk;
        tk_sc[base] = mv;
        float4 bb = ((const float4*)boxes)[(size_t)b * N + mi];
        ((float4*)cand)[base] = bb;
    }
}

// ---------------- Kernel D: greedy NMS + fused compaction, one wave per row ----------
__global__ __launch_bounds__(64) void nms_kernel(
        const float* __restrict__ tk_sc, const float* __restrict__ cand,
        float* __restrict__ cmpval, int* __restrict__ cmpidx,
        int* __restrict__ pcnt, int M, int Cm1) {
    int row = blockIdx.x;
    int b = row / Cm1, c = row % Cm1;
    int lane = threadIdx.x;
    float x1[4], y1[4], x2[4], y2[4], ar[4], sv[4];
    int act[4], kf[4];
    #pragma unroll
    for (int s = 0; s < 4; s++) {
        int j = s * 64 + lane;
        if (j < M_TOP) {
            size_t base = (size_t)row * M_TOP + j;
            float4 bb = ((const float4*)cand)[base];
            x1[s] = bb.x; y1[s] = bb.y; x2[s] = bb.z; y2[s] = bb.w;
            ar[s] = (bb.z - bb.x) * (bb.w - bb.y);
            sv[s] = tk_sc[base];
        } else { x1[s] = 0.f; y1[s] = 0.f; x2[s] = 0.f; y2[s] = 0.f; ar[s] = 0.f; sv[s] = -1.0f; }
        act[s] = (sv[s] > CONF_T) ? 1 : 0;
        kf[s] = 0;
    }
    #pragma unroll
    for (int si = 0; si < 4; si++) {
        int lim = M_TOP - si * 64; if (lim > 64) lim = 64;
        for (int li = 0; li < lim; li++) {
            int a = __shfl(act[si], li);
            if (a) {
                if (lane == li) kf[si] = 1;
                float bx1 = __shfl(x1[si], li);
                float by1 = __shfl(y1[si], li);
                float bx2 = __shfl(x2[si], li);
                float by2 = __shfl(y2[si], li);
                float bar = __shfl(ar[si], li);
                #pragma unroll
                for (int s = 0; s < 4; s++) {
                    float xx1 = fmaxf(bx1, x1[s]);
                    float yy1 = fmaxf(by1, y1[s]);
                    float xx2 = fminf(bx2, x2[s]);
                    float yy2 = fminf(by2, y2[s]);
                    float inter = fmaxf(xx2 - xx1, 0.f) * fmaxf(yy2 - yy1, 0.f);
                    float uni = (ar[s] - inter) + bar;
                    float iou = inter / uni;
                    if (!(iou <= NMS_T)) act[s] = 0;   // NaN suppresses
                }
            }
        }
    }
    unsigned long long ball[4];
    int total = 0;
    #pragma unroll
    for (int s = 0; s < 4; s++) { ball[s] = __ballot(kf[s] != 0); total += (int)__popcll(ball[s]); }
    int base = 0;
    if (lane == 0 && total > 0) base = atomicAdd(&pcnt[b], total);
    base = __shfl(base, 0);
    unsigned long long lower = (lane == 0) ? 0ull : (~0ull >> (64 - lane));
    int off = base;
    #pragma unroll
    for (int s = 0; s < 4; s++) {
        if (kf[s]) {
            int pos = off + (int)__popcll(ball[s] & lower);
            cmpval[(size_t)b * M + pos] = sv[s];
            cmpidx[(size_t)b * M + pos] = c * M_TOP + s * 64 + lane;
        }
        off += (int)__popcll(ball[s]);
    }
}

// ---------------- Kernel E: top-200 of compacted positives, scatter to finsc --------
__global__ __launch_bounds__(256) void gtop_kernel(
        const float* __restrict__ cmpval, const int* __restrict__ cmpidx,
        const int* __restrict__ pcnt, float* __restrict__ finsc, int M) {
    int b = blockIdx.x;
    int tid = threadIdx.x;
    int P = pcnt[b];
    const float* cv = cmpval + (size_t)b * M;
    const int*   ci = cmpidx + (size_t)b * M;
    float* fo = finsc + (size_t)b * M;
    if (P <= M_TOP) {
        for (int i = tid; i < P; i += 256) fo[ci[i]] = cv[i];
        return;
    }
    __shared__ uint32_t hist[256];
    __shared__ uint32_t s_prefix, s_want;
    __shared__ int tiebuf[256];
    __shared__ uint32_t ntie;
    __shared__ int cutoff;
    if (tid == 0) { s_prefix = 0; s_want = M_TOP; }
    for (int pass = 0; pass < 4; pass++) {
        hist[tid] = 0;
        __syncthreads();
        uint32_t prefix = s_prefix;
        int shift = 24 - 8 * pass;
        for (int i = tid; i < P; i += 256) {
            uint32_t k = fkey(cv[i]);
            bool ok = (pass == 0) || ((k >> (shift + 8)) == (prefix >> (shift + 8)));
            if (ok) atomicAdd(&hist[(k >> shift) & 255u], 1u);
        }
        __syncthreads();
        if (tid == 0) {
            uint32_t want = s_want, cum = 0; int bin = 0;
            for (int bb = 255; bb >= 0; bb--) {
                if (cum + hist[bb] >= want) { bin = bb; break; }
                cum += hist[bb];
            }
            s_want = want - cum;
            s_prefix = prefix | ((uint32_t)bin << shift);
        }
        __syncthreads();
    }
    uint32_t kth = s_prefix, rfin = s_want;
    if (tid == 0) { ntie = 0; cutoff = -1; }
    __syncthreads();
    for (int i = tid; i < P; i += 256) {
        if (fkey(cv[i]) == kth) { uint32_t p = atomicAdd(&ntie, 1u); if (p < 256) tiebuf[p] = ci[i]; }
    }
    __syncthreads();
    uint32_t nt = min(ntie, 256u);
    if (tid < (int)nt) {
        int mine = tiebuf[tid];
        uint32_t rk = 0;
        for (uint32_t j = 0; j < nt; j++) if (tiebuf[j] < mine) rk++;
        if (rk == rfin - 1) cutoff = mine;
    }
    __syncthreads();
    int cut = cutoff;
    for (int i = tid; i < P; i += 256) {
        uint32_t k = fkey(cv[i]);
        if (k > kth || (k == kth && ci[i] <= cut)) fo[ci[i]] = cv[i];
    }
}

// ---------------- Kernel F: per-class stable sort + output ----------------
__global__ __launch_bounds__(256) void out_kernel(
        const float* __restrict__ finsc, const float* __restrict__ cand,
        float* __restrict__ out, int C, int Cm1) {
    int row = blockIdx.x;   // b*Cm1 + c
    int b = row / Cm1, c = row % Cm1;
    int tid = threadIdx.x;
    __shared__ float s[M_TOP];
    if (tid < M_TOP) s[tid] = finsc[(size_t)row * M_TOP + tid];
    __syncthreads();
    if (tid < M_TOP) {
        float mv = s[tid];
        uint32_t rk = 0;
        for (int j = 0; j < M_TOP; j++) {
            float jv = s[j];
            if (jv > mv || (jv == mv && j < tid)) rk++;
        }
        size_t obase = (((size_t)(b * C + c + 1)) * M_TOP + rk) * 5;
        out[obase] = mv;
        float4 bb;
        if (mv > 0.f) bb = ((const float4*)cand)[(size_t)row * M_TOP + tid];
        else { bb.x = 0.f; bb.y = 0.f; bb.z = 0.f; bb.w = 0.f; }
        out[obase + 1] = bb.x; out[obase + 2] = bb.y;
        out[obase + 3] = bb.z; out[obase + 4] = bb.w;
    }
}

extern "C" void kernel_launch(void* const* d_in, const int* in_sizes, int n_in,
                              void* d_out, int out_size, void* d_ws, size_t ws_size,
                              hipStream_t stream) {
    const float* loc  = (const float*)d_in[0];
    const float* conf = (const float*)d_in[1];
    const float* dbox = (const float*)d_in[2];
    int N   = in_sizes[2] / 4;
    int B   = in_sizes[0] / (4 * N);
    int C   = in_sizes[1] / (B * N);
    int Cm1 = C - 1;
    int M   = Cm1 * M_TOP;                 // 16000 per batch

    char* ws = (char*)d_ws;
    size_t off = 0;
    auto alloc = [&](size_t bytes) -> char* {
        char* p = ws + off;
        off = (off + bytes + 255) & ~(size_t)255;
        return p;
    };
    float* boxes  = (float*)alloc((size_t)B * N * 4 * sizeof(float));
    float* sc     = (float*)alloc((size_t)B * Cm1 * N * sizeof(float));
    float* tk_sc  = (float*)alloc((size_t)B * M * sizeof(float));
    float* cand   = (float*)alloc((size_t)B * M * 4 * sizeof(float));
    float* finsc  = (float*)alloc((size_t)B * M * sizeof(float));
    int*   pcnt   = (int*)alloc((size_t)B * sizeof(int));
    float* cmpval = (float*)alloc((size_t)B * M * sizeof(float));
    int*   cmpidx = (int*)alloc((size_t)B * M * sizeof(int));

    int bn = B * N;
    decode_kernel<<<(bn + 255) / 256, 256, 0, stream>>>(loc, dbox, boxes, B, N);
    softmax_kernel<<<(bn + SM_ROWS - 1) / SM_ROWS, SM_ROWS, 0, stream>>>(conf, sc, B, N, C);
    topk_kernel<<<B * Cm1, TK_BS, 0, stream>>>(sc, boxes, tk_sc, cand, B, N, Cm1);
    hipMemsetAsync(finsc, 0, (size_t)B * M * sizeof(float) + 256, stream); // finsc + pcnt
    nms_kernel<<<B * Cm1, 64, 0, stream>>>(tk_sc, cand, cmpval, cmpidx, pcnt, M, Cm1);
    gtop_kernel<<<B, 256, 0, stream>>>(cmpval, cmpidx, pcnt, finsc, M);
    hipMemsetAsync(d_out, 0, (size_t)out_size * sizeof(float), stream);
    out_kernel<<<B * Cm1, 256, 0, stream>>>(finsc, cand, (float*)d_out, C, Cm1);
}

// Round 9
// 345.772 us; speedup vs baseline: 2.9052x; 1.0157x over previous
//
#include <hip/hip_runtime.h>
#include <stdint.h>

#define CONF_T 0.01f
#define NMS_T  0.45f
#define M_TOP  200
#define SM_ROWS 64    // rows per softmax block (64 threads); LDS 20.7 KB -> 7 blocks/CU
#define TK_BS  256    // topk block size
#define TCAP   4096   // topk bracket buffer capacity (LDS)

__device__ __forceinline__ uint32_t fkey(float f) {
    uint32_t u = __float_as_uint(f);
    return (u & 0x80000000u) ? ~u : (u | 0x80000000u);
}
__device__ __forceinline__ float fkey_inv(uint32_t k) {
    uint32_t u = (k & 0x80000000u) ? (k & 0x7FFFFFFFu) : ~k;
    return __uint_as_float(u);
}

// Parallel suffix-scan bin selection over nb bins (nb multiple of 256).
__device__ __forceinline__ void suffix_select(
        uint32_t* hist, uint32_t* part, int nb, uint32_t pref, int shift,
        uint32_t wantv, uint32_t* s_prefix, uint32_t* s_want) {
    int tid = threadIdx.x;
    int bpt = nb >> 8;
    int base = tid * bpt;
    uint32_t loc = 0;
    for (int j = 0; j < bpt; j++) loc += hist[base + j];
    part[tid] = loc;
    __syncthreads();
    for (int d = 1; d < 256; d <<= 1) {
        uint32_t y = (tid + d < 256) ? part[tid + d] : 0u;
        __syncthreads();
        part[tid] += y;
        __syncthreads();
    }
    uint32_t run = part[tid] - loc;
    for (int j = bpt - 1; j >= 0; j--) {
        uint32_t h = hist[base + j];
        uint32_t sfx = run + h;
        if (run < wantv && sfx >= wantv) {
            *s_prefix = pref | ((uint32_t)(base + j) << shift);
            *s_want   = wantv - run;
        }
        run = sfx;
    }
    __syncthreads();
}

__device__ __forceinline__ float4 decode_box(float4 l, float4 d) {
    float cx = d.x + (l.x * 0.1f) * d.z;
    float cy = d.y + (l.y * 0.1f) * d.w;
    float w  = d.z * expf(l.z * 0.2f);
    float h  = d.w * expf(l.w * 0.2f);
    float x1 = cx - w * 0.5f, y1 = cy - h * 0.5f;
    float x2 = x1 + w, y2 = y1 + h;
    float4 o;
    o.x = fminf(fmaxf(x1, 0.f), 1.f);
    o.y = fminf(fmaxf(y1, 0.f), 1.f);
    o.z = fminf(fmaxf(x2, 0.f), 1.f);
    o.w = fminf(fmaxf(y2, 0.f), 1.f);
    return o;
}

// ---------------- Kernel B: softmax + transpose (batched-ILP version) ----------------
// Arithmetic is bit-frozen vs the R8-passing version: max is fmax over the
// same values (associative -> tree is safe), sum adds exp terms in exact
// sequential class order, output recomputes expf (same input bits -> same
// output bits) and divides by the same s. Batching only raises ILP.
__global__ __launch_bounds__(SM_ROWS) void softmax_kernel(
        const float* __restrict__ conf, float* __restrict__ sc,
        int B, int N, int C) {
    __shared__ float rows[SM_ROWS * 81];
    int tid = threadIdx.x;
    int BN = B * N;
    long long r0 = (long long)blockIdx.x * SM_ROWS;
    int nrows = BN - (int)r0; if (nrows > SM_ROWS) nrows = SM_ROWS;
    int totalf = nrows * 81;
    const float* g = conf + r0 * 81;
    int total4 = totalf >> 2;
    const float4* g4 = (const float4*)g;
    float4* l4 = (float4*)rows;
    for (int i = tid; i < total4; i += SM_ROWS) l4[i] = g4[i];
    for (int i = (total4 << 2) + tid; i < totalf; i += SM_ROWS) rows[i] = g[i];
    __syncthreads();
    if (tid < nrows) {
        float* p = rows + tid * 81;
        // ---- max: 5 batches of 16 (tree; fmax is associative) ----
        float m = p[0];
        for (int gI = 0; gI < 5; gI++) {
            float r[16];
            #pragma unroll
            for (int j = 0; j < 16; j++) r[j] = p[1 + gI * 16 + j];
            #pragma unroll
            for (int d = 8; d >= 1; d >>= 1)
                #pragma unroll
                for (int j = 0; j < 8; j++) if (j < d) r[j] = fmaxf(r[j], r[j + d]);
            m = fmaxf(m, r[0]);
        }
        // ---- sum: 9 batches of 9 independent expf, sequential adds ----
        float s = 0.f;
        for (int gI = 0; gI < 9; gI++) {
            float e[9];
            #pragma unroll
            for (int j = 0; j < 9; j++) e[j] = expf(p[gI * 9 + j] - m);
            #pragma unroll
            for (int j = 0; j < 9; j++) s += e[j];
        }
        // ---- output: 8 batches of 10 (recomputed expf, IEEE div) ----
        int r = (int)r0 + tid;
        int b = r / N, n = r % N;
        float* obase = sc + ((size_t)b * (C - 1)) * N + n;
        for (int gI = 0; gI < 8; gI++) {
            float e[10];
            #pragma unroll
            for (int j = 0; j < 10; j++) e[j] = expf(p[1 + gI * 10 + j] - m);
            #pragma unroll
            for (int j = 0; j < 10; j++) obase[(size_t)(gI * 10 + j) * N] = e[j] / s;
        }
    }
}

// ---------------- Kernel C: per-row exact top-200 (sample bracket + 1 sweep) ---------
// Also: zeroes pcnt[0..B-1] (consumed by the later nms dispatch) and decodes
// the selected boxes inline from loc/dbox (decode_kernel eliminated).
__global__ __launch_bounds__(TK_BS) void topk_kernel(
        const float* __restrict__ sc, const float* __restrict__ loc,
        const float* __restrict__ dbox,
        float* __restrict__ tk_sc, float* __restrict__ cand,
        int* __restrict__ pcnt,
        int B, int N, int Cm1) {
    const uint32_t KEYN1 = 0x407FFFFFu;        // fkey(-1.0f)
    const uint32_t BIN_N1 = KEYN1 >> 21;       // 0x203
    __shared__ uint32_t hist[2048];
    __shared__ uint32_t part[256];
    __shared__ uint32_t tk[TCAP];
    __shared__ int      tix[TCAP];
    __shared__ uint32_t s_prefix, s_want;
    __shared__ uint32_t ngt, ntie, tcnt;
    __shared__ float    e_val[256];
    __shared__ int      e_idx[256];
    __shared__ int      tiebuf[256];

    int row = blockIdx.x;                      // b*Cm1 + c
    int b = row / Cm1;
    int tid = threadIdx.x;
    if (tid == 0 && row < B) pcnt[row] = 0;    // pcnt init for nms dispatch
    const float* v = sc + (size_t)row * N;
    const float4* v4 = (const float4*)v;
    int n4 = N >> 2;

    // ---- sample phase ----
    bool sampled = (N >= 2048) && ((N & 7) == 0);
    uint32_t lo_key = 0xFFFFFFFFu, hi_key = 0xFFFFFFFFu;
    if (sampled) {
        int stride = N >> 3;
        for (int s = 0; s < 8; s++) {
            float f = v[s * stride + tid];
            tk[s * 256 + tid] = fkey(f > CONF_T ? f : -1.0f);
        }
        for (int i = tid; i < 2048; i += TK_BS) hist[i] = 0;
        __syncthreads();
        for (int i = tid; i < 2048; i += TK_BS) atomicAdd(&hist[tk[i] >> 21], 1u);
        __syncthreads();
        suffix_select(hist, part, 2048, 0u, 21, 3u, &s_prefix, &s_want);
        uint32_t h = s_prefix >> 21;
        suffix_select(hist, part, 2048, 0u, 21, 25u, &s_prefix, &s_want);
        uint32_t l = s_prefix >> 21;
        hi_key = ((h + 1) << 21) - 1u;
        lo_key = (l << 21) - 1u;
        sampled = (l > BIN_N1);
    }

    e_val[tid] = -1.0f; e_idx[tid] = tid;
    if (tid == 0) { ngt = 0; ntie = 0; tcnt = 0; }
    __syncthreads();

    bool ok = false;
    uint32_t G = 0, T = 0;
    if (sampled) {
        for (int i = tid; i < n4; i += TK_BS) {
            float4 f = v4[i];
            float mv[4] = { f.x > CONF_T ? f.x : -1.0f, f.y > CONF_T ? f.y : -1.0f,
                            f.z > CONF_T ? f.z : -1.0f, f.w > CONF_T ? f.w : -1.0f };
            #pragma unroll
            for (int j = 0; j < 4; j++) {
                uint32_t k = fkey(mv[j]);
                if (k > lo_key) {
                    int idx = 4 * i + j;
                    if (k > hi_key) {
                        uint32_t p = atomicAdd(&ngt, 1u);
                        if (p < 256) { e_val[p] = mv[j]; e_idx[p] = idx; }
                    } else {
                        uint32_t p = atomicAdd(&tcnt, 1u);
                        if (p < TCAP) { tk[p] = k; tix[p] = idx; }
                    }
                }
            }
        }
        for (int i = (n4 << 2) + tid; i < N; i += TK_BS) {
            float f = v[i];
            float mv = f > CONF_T ? f : -1.0f;
            uint32_t k = fkey(mv);
            if (k > lo_key) {
                if (k > hi_key) {
                    uint32_t p = atomicAdd(&ngt, 1u);
                    if (p < 256) { e_val[p] = mv; e_idx[p] = i; }
                } else {
                    uint32_t p = atomicAdd(&tcnt, 1u);
                    if (p < TCAP) { tk[p] = k; tix[p] = i; }
                }
            }
        }
        __syncthreads();
        G = ngt; T = tcnt;
        ok = (G <= (uint32_t)M_TOP) && (T <= (uint32_t)TCAP) &&
             (G + T >= (uint32_t)M_TOP);
    }

    uint32_t kth = KEYN1, rfin = 0;
    if (ok) {
        uint32_t want_t = (uint32_t)M_TOP - G;
        if (want_t > 0) {
            for (int i = tid; i < 2048; i += TK_BS) hist[i] = 0;
            __syncthreads();
            for (int i = tid; i < (int)T; i += TK_BS) atomicAdd(&hist[tk[i] >> 21], 1u);
            __syncthreads();
            suffix_select(hist, part, 2048, 0u, 21, want_t, &s_prefix, &s_want);
            uint32_t pre0 = s_prefix, w0 = s_want;
            uint32_t bb0 = pre0 >> 21;
            for (int i = tid; i < 2048; i += TK_BS) hist[i] = 0;
            __syncthreads();
            for (int i = tid; i < (int)T; i += TK_BS)
                if ((tk[i] >> 21) == bb0) atomicAdd(&hist[(tk[i] >> 10) & 2047u], 1u);
            __syncthreads();
            suffix_select(hist, part, 2048, pre0, 10, w0, &s_prefix, &s_want);
            uint32_t pre1 = s_prefix, w1 = s_want;
            for (int i = tid; i < 1024; i += TK_BS) hist[i] = 0;
            __syncthreads();
            for (int i = tid; i < (int)T; i += TK_BS)
                if ((tk[i] >> 10) == (pre1 >> 10)) atomicAdd(&hist[tk[i] & 1023u], 1u);
            __syncthreads();
            suffix_select(hist, part, 1024, pre1, 0, w1, &s_prefix, &s_want);
            kth = s_prefix; rfin = s_want;
            for (int i = tid; i < (int)T; i += TK_BS) {
                uint32_t k = tk[i];
                if (k > kth) {
                    uint32_t p = atomicAdd(&ngt, 1u);
                    if (p < 256) { e_val[p] = fkey_inv(k); e_idx[p] = tix[i]; }
                } else if (k == kth) {
                    uint32_t p = atomicAdd(&ntie, 1u);
                    if (p < 256) tiebuf[p] = tix[i];
                }
            }
            __syncthreads();
        }
    } else {
        // ---- fallback: exact 2-sweep histogram path ----
        e_val[tid] = -1.0f; e_idx[tid] = tid;
        if (tid == 0) { ngt = 0; ntie = 0; tcnt = 0; }
        for (int i = tid; i < 2048; i += TK_BS) hist[i] = 0;
        __syncthreads();
        for (int i = tid; i < n4; i += TK_BS) {
            float4 f = v4[i];
            atomicAdd(&hist[fkey(f.x > CONF_T ? f.x : -1.0f) >> 21], 1u);
            atomicAdd(&hist[fkey(f.y > CONF_T ? f.y : -1.0f) >> 21], 1u);
            atomicAdd(&hist[fkey(f.z > CONF_T ? f.z : -1.0f) >> 21], 1u);
            atomicAdd(&hist[fkey(f.w > CONF_T ? f.w : -1.0f) >> 21], 1u);
        }
        for (int i = (n4 << 2) + tid; i < N; i += TK_BS)
            atomicAdd(&hist[fkey(v[i] > CONF_T ? v[i] : -1.0f) >> 21], 1u);
        __syncthreads();
        suffix_select(hist, part, 2048, 0u, 21, M_TOP, &s_prefix, &s_want);
        uint32_t b0 = s_prefix >> 21;
        uint32_t want1 = s_want;
        bool collect_ties = (b0 != BIN_N1);
        for (int i = tid; i < N; i += TK_BS) {
            float f = v[i];
            float mv = f > CONF_T ? f : -1.0f;
            uint32_t k = fkey(mv);
            uint32_t bin = k >> 21;
            if (bin > b0) {
                uint32_t p = atomicAdd(&ngt, 1u);
                if (p < 256) { e_val[p] = mv; e_idx[p] = i; }
            } else if (bin == b0 && collect_ties) {
                uint32_t p = atomicAdd(&tcnt, 1u);
                if (p < TCAP) { tk[p] = k; tix[p] = i; }
            }
        }
        __syncthreads();
        if (collect_ties && tcnt <= TCAP) {
            int Tl = (int)tcnt;
            for (int i = tid; i < 2048; i += TK_BS) hist[i] = 0;
            __syncthreads();
            for (int i = tid; i < Tl; i += TK_BS) atomicAdd(&hist[(tk[i] >> 10) & 2047u], 1u);
            __syncthreads();
            suffix_select(hist, part, 2048, b0 << 21, 10, want1, &s_prefix, &s_want);
            uint32_t pre2 = s_prefix; uint32_t want2 = s_want;
            uint32_t b1 = (pre2 >> 10) & 2047u;
            for (int i = tid; i < 1024; i += TK_BS) hist[i] = 0;
            __syncthreads();
            for (int i = tid; i < Tl; i += TK_BS)
                if (((tk[i] >> 10) & 2047u) == b1) atomicAdd(&hist[tk[i] & 1023u], 1u);
            __syncthreads();
            suffix_select(hist, part, 1024, pre2, 0, want2, &s_prefix, &s_want);
            kth = s_prefix; rfin = s_want;
            for (int i = tid; i < Tl; i += TK_BS) {
                uint32_t k = tk[i];
                if (k > kth) {
                    uint32_t p = atomicAdd(&ngt, 1u);
                    if (p < 256) { e_val[p] = fkey_inv(k); e_idx[p] = tix[i]; }
                } else if (k == kth) {
                    uint32_t p = atomicAdd(&ntie, 1u);
                    if (p < 256) tiebuf[p] = tix[i];
                }
            }
            __syncthreads();
        } else if (collect_ties) {
            const int shifts[2] = {10, 0};
            const int nbins_[2] = {2048, 1024};
            if (tid == 0) { s_prefix = b0 << 21; s_want = want1; }
            __syncthreads();
            for (int lev = 0; lev < 2; lev++) {
                int shift = shifts[lev];
                int nb = nbins_[lev];
                uint32_t bmask = (uint32_t)nb - 1u;
                uint32_t pref = s_prefix, wantv = s_want;
                uint32_t pmask = 0xFFFFFFFFu << (shift + ((nb == 2048) ? 11 : 10));
                for (int i = tid; i < nb; i += TK_BS) hist[i] = 0;
                __syncthreads();
                for (int i = tid; i < N; i += TK_BS) {
                    float f = v[i];
                    uint32_t k = fkey(f > CONF_T ? f : -1.0f);
                    if ((k & pmask) == (pref & pmask)) atomicAdd(&hist[(k >> shift) & bmask], 1u);
                }
                __syncthreads();
                suffix_select(hist, part, nb, pref, shift, wantv, &s_prefix, &s_want);
            }
            kth = s_prefix; rfin = s_want;
            for (int i = tid; i < N; i += TK_BS) {
                float f = v[i];
                float mv = f > CONF_T ? f : -1.0f;
                uint32_t k = fkey(mv);
                if ((k >> 21) == b0) {
                    if (k > kth) {
                        uint32_t p = atomicAdd(&ngt, 1u);
                        if (p < 256) { e_val[p] = mv; e_idx[p] = i; }
                    } else if (k == kth) {
                        uint32_t p = atomicAdd(&ntie, 1u);
                        if (p < 256) tiebuf[p] = i;
                    }
                }
            }
            __syncthreads();
        }
    }

    // ---- shared epilogue: ties, rank order, inline box decode ----
    uint32_t gcount = min(ngt, (uint32_t)M_TOP);
    uint32_t nt = min(ntie, 256u);
    if (tid < (int)nt) {
        int mine = tiebuf[tid];
        uint32_t rk = 0;
        for (uint32_t j = 0; j < nt; j++) if (tiebuf[j] < mine) rk++;
        if (rk < rfin) {
            uint32_t slot = gcount + rk;
            if (slot < M_TOP) { e_val[slot] = fkey_inv(kth); e_idx[slot] = mine; }
        }
    }
    __syncthreads();
    if (tid < M_TOP) {
        float mv = e_val[tid]; int mi = e_idx[tid];
        uint32_t mk = fkey(mv);
        uint32_t rk = 0;
        for (int j = 0; j < M_TOP; j++) {
            uint32_t jk = fkey(e_val[j]); int ji = e_idx[j];
            if (jk > mk || (jk == mk && ji < mi)) rk++;
        }
        size_t base = (size_t)row * M_TOP + rk;
        tk_sc[base] = mv;
        float4 l = ((const float4*)loc)[(size_t)b * N + mi];
        float4 d = ((const float4*)dbox)[mi];
        ((float4*)cand)[base] = decode_box(l, d);
    }
}

// ---------------- Kernel D: greedy NMS + fused compaction, one wave per row ----------
__global__ __launch_bounds__(64) void nms_kernel(
        const float* __restrict__ tk_sc, const float* __restrict__ cand,
        float* __restrict__ cmpval, int* __restrict__ cmpidx,
        int* __restrict__ pcnt, int M, int Cm1) {
    int row = blockIdx.x;
    int b = row / Cm1, c = row % Cm1;
    int lane = threadIdx.x;
    float x1[4], y1[4], x2[4], y2[4], ar[4], sv[4];
    int act[4], kf[4];
    #pragma unroll
    for (int s = 0; s < 4; s++) {
        int j = s * 64 + lane;
        if (j < M_TOP) {
            size_t base = (size_t)row * M_TOP + j;
            float4 bb = ((const float4*)cand)[base];
            x1[s] = bb.x; y1[s] = bb.y; x2[s] = bb.z; y2[s] = bb.w;
            ar[s] = (bb.z - bb.x) * (bb.w - bb.y);
            sv[s] = tk_sc[base];
        } else { x1[s] = 0.f; y1[s] = 0.f; x2[s] = 0.f; y2[s] = 0.f; ar[s] = 0.f; sv[s] = -1.0f; }
        act[s] = (sv[s] > CONF_T) ? 1 : 0;
        kf[s] = 0;
    }
    #pragma unroll
    for (int si = 0; si < 4; si++) {
        int lim = M_TOP - si * 64; if (lim > 64) lim = 64;
        for (int li = 0; li < lim; li++) {
            int a = __shfl(act[si], li);
            if (a) {
                if (lane == li) kf[si] = 1;
                float bx1 = __shfl(x1[si], li);
                float by1 = __shfl(y1[si], li);
                float bx2 = __shfl(x2[si], li);
                float by2 = __shfl(y2[si], li);
                float bar = __shfl(ar[si], li);
                #pragma unroll
                for (int s = 0; s < 4; s++) {
                    float xx1 = fmaxf(bx1, x1[s]);
                    float yy1 = fmaxf(by1, y1[s]);
                    float xx2 = fminf(bx2, x2[s]);
                    float yy2 = fminf(by2, y2[s]);
                    float inter = fmaxf(xx2 - xx1, 0.f) * fmaxf(yy2 - yy1, 0.f);
                    float uni = (ar[s] - inter) + bar;
                    float iou = inter / uni;
                    if (!(iou <= NMS_T)) act[s] = 0;   // NaN suppresses
                }
            }
        }
    }
    unsigned long long ball[4];
    int total = 0;
    #pragma unroll
    for (int s = 0; s < 4; s++) { ball[s] = __ballot(kf[s] != 0); total += (int)__popcll(ball[s]); }
    int base = 0;
    if (lane == 0 && total > 0) base = atomicAdd(&pcnt[b], total);
    base = __shfl(base, 0);
    unsigned long long lower = (lane == 0) ? 0ull : (~0ull >> (64 - lane));
    int off = base;
    #pragma unroll
    for (int s = 0; s < 4; s++) {
        if (kf[s]) {
            int pos = off + (int)__popcll(ball[s] & lower);
            cmpval[(size_t)b * M + pos] = sv[s];
            cmpidx[(size_t)b * M + pos] = c * M_TOP + s * 64 + lane;
        }
        off += (int)__popcll(ball[s]);
    }
}

// ---------------- Kernel E: top-200 of positives -> compact (val,idx) list ----------
__global__ __launch_bounds__(256) void gtop_kernel(
        const float* __restrict__ cmpval, const int* __restrict__ cmpidx,
        const int* __restrict__ pcnt, float* __restrict__ gl_val,
        int* __restrict__ gl_idx, int* __restrict__ gl_cnt, int M) {
    int b = blockIdx.x;
    int tid = threadIdx.x;
    int P = pcnt[b];
    const float* cv = cmpval + (size_t)b * M;
    const int*   ci = cmpidx + (size_t)b * M;
    if (P <= M_TOP) {
        for (int i = tid; i < P; i += 256) {
            gl_val[b * M_TOP + i] = cv[i];
            gl_idx[b * M_TOP + i] = ci[i];
        }
        if (tid == 0) gl_cnt[b] = P;
        return;
    }
    __shared__ uint32_t hist[256];
    __shared__ uint32_t s_prefix, s_want;
    __shared__ int tiebuf[256];
    __shared__ uint32_t ntie, wcnt;
    __shared__ int cutoff;
    if (tid == 0) { s_prefix = 0; s_want = M_TOP; }
    for (int pass = 0; pass < 4; pass++) {
        hist[tid] = 0;
        __syncthreads();
        uint32_t prefix = s_prefix;
        int shift = 24 - 8 * pass;
        for (int i = tid; i < P; i += 256) {
            uint32_t k = fkey(cv[i]);
            bool ok = (pass == 0) || ((k >> (shift + 8)) == (prefix >> (shift + 8)));
            if (ok) atomicAdd(&hist[(k >> shift) & 255u], 1u);
        }
        __syncthreads();
        if (tid == 0) {
            uint32_t want = s_want, cum = 0; int bin = 0;
            for (int bb = 255; bb >= 0; bb--) {
                if (cum + hist[bb] >= want) { bin = bb; break; }
                cum += hist[bb];
            }
            s_want = want - cum;
            s_prefix = prefix | ((uint32_t)bin << shift);
        }
        __syncthreads();
    }
    uint32_t kth = s_prefix, rfin = s_want;
    if (tid == 0) { ntie = 0; cutoff = -1; wcnt = 0; }
    __syncthreads();
    for (int i = tid; i < P; i += 256) {
        if (fkey(cv[i]) == kth) { uint32_t p = atomicAdd(&ntie, 1u); if (p < 256) tiebuf[p] = ci[i]; }
    }
    __syncthreads();
    uint32_t nt = min(ntie, 256u);
    if (tid < (int)nt) {
        int mine = tiebuf[tid];
        uint32_t rk = 0;
        for (uint32_t j = 0; j < nt; j++) if (tiebuf[j] < mine) rk++;
        if (rk == rfin - 1) cutoff = mine;
    }
    __syncthreads();
    int cut = cutoff;
    for (int i = tid; i < P; i += 256) {
        uint32_t k = fkey(cv[i]);
        if (k > kth || (k == kth && ci[i] <= cut)) {
            uint32_t p = atomicAdd(&wcnt, 1u);     // exactly M_TOP selected
            gl_val[b * M_TOP + p] = cv[i];
            gl_idx[b * M_TOP + p] = ci[i];
        }
    }
    if (tid == 0) gl_cnt[b] = M_TOP;
}

// ---------------- Kernel F: per-class sort + FULL output write (no memset) ----------
__global__ __launch_bounds__(256) void out_kernel(
        const float* __restrict__ gl_val, const int* __restrict__ gl_idx,
        const int* __restrict__ gl_cnt, const float* __restrict__ cand,
        float* __restrict__ out, int C, int Cm1) {
    int row = blockIdx.x;   // b*C + cc
    int b = row / C, cc = row % C;
    int tid = threadIdx.x;
    size_t oslab = (size_t)row * M_TOP * 5;
    if (cc == 0) {                         // background class: all zeros
        for (int i = tid; i < M_TOP * 5; i += 256) out[oslab + i] = 0.0f;
        return;
    }
    int c = cc - 1;
    __shared__ float lv[M_TOP];
    __shared__ int   lm[M_TOP];
    __shared__ uint32_t nloc;
    if (tid == 0) nloc = 0;
    __syncthreads();
    int cnt = gl_cnt[b];
    for (int i = tid; i < cnt; i += 256) {
        int idx = gl_idx[b * M_TOP + i];
        if (idx / M_TOP == c) {
            uint32_t p = atomicAdd(&nloc, 1u);
            lv[p] = gl_val[b * M_TOP + i];
            lm[p] = idx % M_TOP;
        }
    }
    __syncthreads();
    int nc = (int)nloc;
    if (tid < M_TOP) {
        if (tid < nc) {
            float v = lv[tid]; int m = lm[tid];
            int rk = 0;
            for (int j = 0; j < nc; j++)
                if (lv[j] > v || (lv[j] == v && lm[j] < m)) rk++;
            float4 bb = ((const float4*)cand)[((size_t)(b * Cm1 + c)) * M_TOP + m];
            size_t o = oslab + (size_t)rk * 5;
            out[o] = v; out[o + 1] = bb.x; out[o + 2] = bb.y;
            out[o + 3] = bb.z; out[o + 4] = bb.w;
        } else {
            size_t o = oslab + (size_t)tid * 5;
            out[o] = 0.f; out[o + 1] = 0.f; out[o + 2] = 0.f;
            out[o + 3] = 0.f; out[o + 4] = 0.f;
        }
    }
}

extern "C" void kernel_launch(void* const* d_in, const int* in_sizes, int n_in,
                              void* d_out, int out_size, void* d_ws, size_t ws_size,
                              hipStream_t stream) {
    const float* loc  = (const float*)d_in[0];
    const float* conf = (const float*)d_in[1];
    const float* dbox = (const float*)d_in[2];
    int N   = in_sizes[2] / 4;
    int B   = in_sizes[0] / (4 * N);
    int C   = in_sizes[1] / (B * N);
    int Cm1 = C - 1;
    int M   = Cm1 * M_TOP;                 // 16000 per batch

    char* ws = (char*)d_ws;
    size_t off = 0;
    auto alloc = [&](size_t bytes) -> char* {
        char* p = ws + off;
        off = (off + bytes + 255) & ~(size_t)255;
        return p;
    };
    float* sc     = (float*)alloc((size_t)B * Cm1 * N * sizeof(float));
    float* tk_sc  = (float*)alloc((size_t)B * M * sizeof(float));
    float* cand   = (float*)alloc((size_t)B * M * 4 * sizeof(float));
    int*   pcnt   = (int*)alloc((size_t)B * sizeof(int));
    float* cmpval = (float*)alloc((size_t)B * M * sizeof(float));
    int*   cmpidx = (int*)alloc((size_t)B * M * sizeof(int));
    float* gl_val = (float*)alloc((size_t)B * M_TOP * sizeof(float));
    int*   gl_idx = (int*)alloc((size_t)B * M_TOP * sizeof(int));
    int*   gl_cnt = (int*)alloc((size_t)B * sizeof(int));

    int bn = B * N;
    softmax_kernel<<<(bn + SM_ROWS - 1) / SM_ROWS, SM_ROWS, 0, stream>>>(conf, sc, B, N, C);
    topk_kernel<<<B * Cm1, TK_BS, 0, stream>>>(sc, loc, dbox, tk_sc, cand, pcnt, B, N, Cm1);
    nms_kernel<<<B * Cm1, 64, 0, stream>>>(tk_sc, cand, cmpval, cmpidx, pcnt, M, Cm1);
    gtop_kernel<<<B, 256, 0, stream>>>(cmpval, cmpidx, pcnt, gl_val, gl_idx, gl_cnt, M);
    out_kernel<<<B * C, 256, 0, stream>>>(gl_val, gl_idx, gl_cnt, cand, (float*)d_out, C, Cm1);
}

// Round 10
// 335.381 us; speedup vs baseline: 2.9952x; 1.0310x over previous
//
#include <hip/hip_runtime.h>
#include <stdint.h>

#define CONF_T 0.01f
#define NMS_T  0.45f
#define M_TOP  200
#define SM_ROWS 64    // rows per softmax block (64 threads); LDS 20.7 KB -> 7 blocks/CU
#define TK_BS  256    // topk block size
#define TCAP   4096   // topk bracket buffer capacity (LDS)

__device__ __forceinline__ uint32_t fkey(float f) {
    uint32_t u = __float_as_uint(f);
    return (u & 0x80000000u) ? ~u : (u | 0x80000000u);
}
__device__ __forceinline__ float fkey_inv(uint32_t k) {
    uint32_t u = (k & 0x80000000u) ? (k & 0x7FFFFFFFu) : ~k;
    return __uint_as_float(u);
}

// Parallel suffix-scan bin selection over nb bins (nb multiple of 256).
__device__ __forceinline__ void suffix_select(
        uint32_t* hist, uint32_t* part, int nb, uint32_t pref, int shift,
        uint32_t wantv, uint32_t* s_prefix, uint32_t* s_want) {
    int tid = threadIdx.x;
    int bpt = nb >> 8;
    int base = tid * bpt;
    uint32_t loc = 0;
    for (int j = 0; j < bpt; j++) loc += hist[base + j];
    part[tid] = loc;
    __syncthreads();
    for (int d = 1; d < 256; d <<= 1) {
        uint32_t y = (tid + d < 256) ? part[tid + d] : 0u;
        __syncthreads();
        part[tid] += y;
        __syncthreads();
    }
    uint32_t run = part[tid] - loc;
    for (int j = bpt - 1; j >= 0; j--) {
        uint32_t h = hist[base + j];
        uint32_t sfx = run + h;
        if (run < wantv && sfx >= wantv) {
            *s_prefix = pref | ((uint32_t)(base + j) << shift);
            *s_want   = wantv - run;
        }
        run = sfx;
    }
    __syncthreads();
}

__device__ __forceinline__ float4 decode_box(float4 l, float4 d) {
    float cx = d.x + (l.x * 0.1f) * d.z;
    float cy = d.y + (l.y * 0.1f) * d.w;
    float w  = d.z * expf(l.z * 0.2f);
    float h  = d.w * expf(l.w * 0.2f);
    float x1 = cx - w * 0.5f, y1 = cy - h * 0.5f;
    float x2 = x1 + w, y2 = y1 + h;
    float4 o;
    o.x = fminf(fmaxf(x1, 0.f), 1.f);
    o.y = fminf(fmaxf(y1, 0.f), 1.f);
    o.z = fminf(fmaxf(x2, 0.f), 1.f);
    o.w = fminf(fmaxf(y2, 0.f), 1.f);
    return o;
}

// ---------------- Kernel B: softmax + transpose (R8-proven form) ----------------
__global__ __launch_bounds__(SM_ROWS) void softmax_kernel(
        const float* __restrict__ conf, float* __restrict__ sc,
        int B, int N, int C) {
    __shared__ float rows[SM_ROWS * 81];
    int tid = threadIdx.x;
    int BN = B * N;
    long long r0 = (long long)blockIdx.x * SM_ROWS;
    int nrows = BN - (int)r0; if (nrows > SM_ROWS) nrows = SM_ROWS;
    int totalf = nrows * 81;
    const float* g = conf + r0 * 81;
    int total4 = totalf >> 2;
    const float4* g4 = (const float4*)g;
    float4* l4 = (float4*)rows;
    for (int i = tid; i < total4; i += SM_ROWS) l4[i] = g4[i];
    for (int i = (total4 << 2) + tid; i < totalf; i += SM_ROWS) rows[i] = g[i];
    __syncthreads();
    if (tid < nrows) {
        float* p = rows + tid * 81;
        float m = p[0];
        for (int c = 1; c < 81; c++) m = fmaxf(m, p[c]);
        float s = 0.f;
        for (int c = 0; c < 81; c++) { float e = expf(p[c] - m); p[c] = e; s += e; }
        int r = (int)r0 + tid;
        int b = r / N, n = r % N;
        size_t base = ((size_t)b * (C - 1)) * N + n;
        for (int c = 1; c < 81; c++) {
            sc[base + (size_t)(c - 1) * N] = p[c] / s;
        }
    }
}

// ---------------- Kernel C: top-200 (sample bracket) + inline decode + FUSED NMS -----
// After rank-ordering, the sorted top-200 (score + decoded box) sits in LDS;
// wave 0 runs the register/shuffle greedy NMS (no barriers) and ballot-
// compacts survivors into (cmpval,cmpidx) with ONE pcnt atomic per row.
// pcnt must be pre-zeroed by the host-side memset (atomicAdd race otherwise).
__global__ __launch_bounds__(TK_BS) void topk_kernel(
        const float* __restrict__ sc, const float* __restrict__ loc,
        const float* __restrict__ dbox,
        float* __restrict__ cand,
        float* __restrict__ cmpval, int* __restrict__ cmpidx,
        int* __restrict__ pcnt,
        int B, int N, int Cm1, int M) {
    const uint32_t KEYN1 = 0x407FFFFFu;        // fkey(-1.0f)
    const uint32_t BIN_N1 = KEYN1 >> 21;       // 0x203
    __shared__ uint32_t hist[2048];
    __shared__ uint32_t part[256];
    __shared__ uint32_t tk[TCAP];
    __shared__ int      tix[TCAP];
    __shared__ uint32_t s_prefix, s_want;
    __shared__ uint32_t ngt, ntie, tcnt;
    __shared__ float    e_val[256];
    __shared__ int      e_idx[256];
    __shared__ int      tiebuf[256];
    __shared__ float    s_sc[M_TOP];
    __shared__ float    s_x1[M_TOP], s_y1[M_TOP], s_x2[M_TOP], s_y2[M_TOP];

    int row = blockIdx.x;                      // b*Cm1 + c
    int b = row / Cm1, c = row % Cm1;
    int tid = threadIdx.x;
    const float* v = sc + (size_t)row * N;
    const float4* v4 = (const float4*)v;
    int n4 = N >> 2;

    // ---- sample phase ----
    bool sampled = (N >= 2048) && ((N & 7) == 0);
    uint32_t lo_key = 0xFFFFFFFFu, hi_key = 0xFFFFFFFFu;
    if (sampled) {
        int stride = N >> 3;
        for (int s = 0; s < 8; s++) {
            float f = v[s * stride + tid];
            tk[s * 256 + tid] = fkey(f > CONF_T ? f : -1.0f);
        }
        for (int i = tid; i < 2048; i += TK_BS) hist[i] = 0;
        __syncthreads();
        for (int i = tid; i < 2048; i += TK_BS) atomicAdd(&hist[tk[i] >> 21], 1u);
        __syncthreads();
        suffix_select(hist, part, 2048, 0u, 21, 3u, &s_prefix, &s_want);
        uint32_t h = s_prefix >> 21;
        suffix_select(hist, part, 2048, 0u, 21, 25u, &s_prefix, &s_want);
        uint32_t l = s_prefix >> 21;
        hi_key = ((h + 1) << 21) - 1u;
        lo_key = (l << 21) - 1u;
        sampled = (l > BIN_N1);
    }

    e_val[tid] = -1.0f; e_idx[tid] = tid;
    if (tid == 0) { ngt = 0; ntie = 0; tcnt = 0; }
    __syncthreads();

    bool ok = false;
    uint32_t G = 0, T = 0;
    if (sampled) {
        for (int i = tid; i < n4; i += TK_BS) {
            float4 f = v4[i];
            float mv[4] = { f.x > CONF_T ? f.x : -1.0f, f.y > CONF_T ? f.y : -1.0f,
                            f.z > CONF_T ? f.z : -1.0f, f.w > CONF_T ? f.w : -1.0f };
            #pragma unroll
            for (int j = 0; j < 4; j++) {
                uint32_t k = fkey(mv[j]);
                if (k > lo_key) {
                    int idx = 4 * i + j;
                    if (k > hi_key) {
                        uint32_t p = atomicAdd(&ngt, 1u);
                        if (p < 256) { e_val[p] = mv[j]; e_idx[p] = idx; }
                    } else {
                        uint32_t p = atomicAdd(&tcnt, 1u);
                        if (p < TCAP) { tk[p] = k; tix[p] = idx; }
                    }
                }
            }
        }
        for (int i = (n4 << 2) + tid; i < N; i += TK_BS) {
            float f = v[i];
            float mv = f > CONF_T ? f : -1.0f;
            uint32_t k = fkey(mv);
            if (k > lo_key) {
                if (k > hi_key) {
                    uint32_t p = atomicAdd(&ngt, 1u);
                    if (p < 256) { e_val[p] = mv; e_idx[p] = i; }
                } else {
                    uint32_t p = atomicAdd(&tcnt, 1u);
                    if (p < TCAP) { tk[p] = k; tix[p] = i; }
                }
            }
        }
        __syncthreads();
        G = ngt; T = tcnt;
        ok = (G <= (uint32_t)M_TOP) && (T <= (uint32_t)TCAP) &&
             (G + T >= (uint32_t)M_TOP);
    }

    uint32_t kth = KEYN1, rfin = 0;
    if (ok) {
        uint32_t want_t = (uint32_t)M_TOP - G;
        if (want_t > 0) {
            for (int i = tid; i < 2048; i += TK_BS) hist[i] = 0;
            __syncthreads();
            for (int i = tid; i < (int)T; i += TK_BS) atomicAdd(&hist[tk[i] >> 21], 1u);
            __syncthreads();
            suffix_select(hist, part, 2048, 0u, 21, want_t, &s_prefix, &s_want);
            uint32_t pre0 = s_prefix, w0 = s_want;
            uint32_t bb0 = pre0 >> 21;
            for (int i = tid; i < 2048; i += TK_BS) hist[i] = 0;
            __syncthreads();
            for (int i = tid; i < (int)T; i += TK_BS)
                if ((tk[i] >> 21) == bb0) atomicAdd(&hist[(tk[i] >> 10) & 2047u], 1u);
            __syncthreads();
            suffix_select(hist, part, 2048, pre0, 10, w0, &s_prefix, &s_want);
            uint32_t pre1 = s_prefix, w1 = s_want;
            for (int i = tid; i < 1024; i += TK_BS) hist[i] = 0;
            __syncthreads();
            for (int i = tid; i < (int)T; i += TK_BS)
                if ((tk[i] >> 10) == (pre1 >> 10)) atomicAdd(&hist[tk[i] & 1023u], 1u);
            __syncthreads();
            suffix_select(hist, part, 1024, pre1, 0, w1, &s_prefix, &s_want);
            kth = s_prefix; rfin = s_want;
            for (int i = tid; i < (int)T; i += TK_BS) {
                uint32_t k = tk[i];
                if (k > kth) {
                    uint32_t p = atomicAdd(&ngt, 1u);
                    if (p < 256) { e_val[p] = fkey_inv(k); e_idx[p] = tix[i]; }
                } else if (k == kth) {
                    uint32_t p = atomicAdd(&ntie, 1u);
                    if (p < 256) tiebuf[p] = tix[i];
                }
            }
            __syncthreads();
        }
    } else {
        // ---- fallback: exact 2-sweep histogram path ----
        e_val[tid] = -1.0f; e_idx[tid] = tid;
        if (tid == 0) { ngt = 0; ntie = 0; tcnt = 0; }
        for (int i = tid; i < 2048; i += TK_BS) hist[i] = 0;
        __syncthreads();
        for (int i = tid; i < n4; i += TK_BS) {
            float4 f = v4[i];
            atomicAdd(&hist[fkey(f.x > CONF_T ? f.x : -1.0f) >> 21], 1u);
            atomicAdd(&hist[fkey(f.y > CONF_T ? f.y : -1.0f) >> 21], 1u);
            atomicAdd(&hist[fkey(f.z > CONF_T ? f.z : -1.0f) >> 21], 1u);
            atomicAdd(&hist[fkey(f.w > CONF_T ? f.w : -1.0f) >> 21], 1u);
        }
        for (int i = (n4 << 2) + tid; i < N; i += TK_BS)
            atomicAdd(&hist[fkey(v[i] > CONF_T ? v[i] : -1.0f) >> 21], 1u);
        __syncthreads();
        suffix_select(hist, part, 2048, 0u, 21, M_TOP, &s_prefix, &s_want);
        uint32_t b0 = s_prefix >> 21;
        uint32_t want1 = s_want;
        bool collect_ties = (b0 != BIN_N1);
        for (int i = tid; i < N; i += TK_BS) {
            float f = v[i];
            float mv = f > CONF_T ? f : -1.0f;
            uint32_t k = fkey(mv);
            uint32_t bin = k >> 21;
            if (bin > b0) {
                uint32_t p = atomicAdd(&ngt, 1u);
                if (p < 256) { e_val[p] = mv; e_idx[p] = i; }
            } else if (bin == b0 && collect_ties) {
                uint32_t p = atomicAdd(&tcnt, 1u);
                if (p < TCAP) { tk[p] = k; tix[p] = i; }
            }
        }
        __syncthreads();
        if (collect_ties && tcnt <= TCAP) {
            int Tl = (int)tcnt;
            for (int i = tid; i < 2048; i += TK_BS) hist[i] = 0;
            __syncthreads();
            for (int i = tid; i < Tl; i += TK_BS) atomicAdd(&hist[(tk[i] >> 10) & 2047u], 1u);
            __syncthreads();
            suffix_select(hist, part, 2048, b0 << 21, 10, want1, &s_prefix, &s_want);
            uint32_t pre2 = s_prefix; uint32_t want2 = s_want;
            uint32_t b1 = (pre2 >> 10) & 2047u;
            for (int i = tid; i < 1024; i += TK_BS) hist[i] = 0;
            __syncthreads();
            for (int i = tid; i < Tl; i += TK_BS)
                if (((tk[i] >> 10) & 2047u) == b1) atomicAdd(&hist[tk[i] & 1023u], 1u);
            __syncthreads();
            suffix_select(hist, part, 1024, pre2, 0, want2, &s_prefix, &s_want);
            kth = s_prefix; rfin = s_want;
            for (int i = tid; i < Tl; i += TK_BS) {
                uint32_t k = tk[i];
                if (k > kth) {
                    uint32_t p = atomicAdd(&ngt, 1u);
                    if (p < 256) { e_val[p] = fkey_inv(k); e_idx[p] = tix[i]; }
                } else if (k == kth) {
                    uint32_t p = atomicAdd(&ntie, 1u);
                    if (p < 256) tiebuf[p] = tix[i];
                }
            }
            __syncthreads();
        } else if (collect_ties) {
            const int shifts[2] = {10, 0};
            const int nbins_[2] = {2048, 1024};
            if (tid == 0) { s_prefix = b0 << 21; s_want = want1; }
            __syncthreads();
            for (int lev = 0; lev < 2; lev++) {
                int shift = shifts[lev];
                int nb = nbins_[lev];
                uint32_t bmask = (uint32_t)nb - 1u;
                uint32_t pref = s_prefix, wantv = s_want;
                uint32_t pmask = 0xFFFFFFFFu << (shift + ((nb == 2048) ? 11 : 10));
                for (int i = tid; i < nb; i += TK_BS) hist[i] = 0;
                __syncthreads();
                for (int i = tid; i < N; i += TK_BS) {
                    float f = v[i];
                    uint32_t k = fkey(f > CONF_T ? f : -1.0f);
                    if ((k & pmask) == (pref & pmask)) atomicAdd(&hist[(k >> shift) & bmask], 1u);
                }
                __syncthreads();
                suffix_select(hist, part, nb, pref, shift, wantv, &s_prefix, &s_want);
            }
            kth = s_prefix; rfin = s_want;
            for (int i = tid; i < N; i += TK_BS) {
                float f = v[i];
                float mv = f > CONF_T ? f : -1.0f;
                uint32_t k = fkey(mv);
                if ((k >> 21) == b0) {
                    if (k > kth) {
                        uint32_t p = atomicAdd(&ngt, 1u);
                        if (p < 256) { e_val[p] = mv; e_idx[p] = i; }
                    } else if (k == kth) {
                        uint32_t p = atomicAdd(&ntie, 1u);
                        if (p < 256) tiebuf[p] = i;
                    }
                }
            }
            __syncthreads();
        }
    }

    // ---- ties, rank order, inline box decode -> LDS + cand ----
    uint32_t gcount = min(ngt, (uint32_t)M_TOP);
    uint32_t nt = min(ntie, 256u);
    if (tid < (int)nt) {
        int mine = tiebuf[tid];
        uint32_t rk = 0;
        for (uint32_t j = 0; j < nt; j++) if (tiebuf[j] < mine) rk++;
        if (rk < rfin) {
            uint32_t slot = gcount + rk;
            if (slot < M_TOP) { e_val[slot] = fkey_inv(kth); e_idx[slot] = mine; }
        }
    }
    __syncthreads();
    if (tid < M_TOP) {
        float mv = e_val[tid]; int mi = e_idx[tid];
        uint32_t mk = fkey(mv);
        uint32_t rk = 0;
        for (int j = 0; j < M_TOP; j++) {
            uint32_t jk = fkey(e_val[j]); int ji = e_idx[j];
            if (jk > mk || (jk == mk && ji < mi)) rk++;
        }
        float4 l = ((const float4*)loc)[(size_t)b * N + mi];
        float4 d = ((const float4*)dbox)[mi];
        float4 bx = decode_box(l, d);
        ((float4*)cand)[(size_t)row * M_TOP + rk] = bx;   // for out_kernel gather
        s_sc[rk] = mv;
        s_x1[rk] = bx.x; s_y1[rk] = bx.y; s_x2[rk] = bx.z; s_y2[rk] = bx.w;
    }
    __syncthreads();

    // ---- fused greedy NMS + compaction on wave 0 (shuffle-only, no barriers) ----
    if (tid < 64) {
        int lane = tid;
        float x1[4], y1[4], x2[4], y2[4], ar[4], sv[4];
        int act[4], kf[4];
        #pragma unroll
        for (int s = 0; s < 4; s++) {
            int j = s * 64 + lane;
            if (j < M_TOP) {
                x1[s] = s_x1[j]; y1[s] = s_y1[j]; x2[s] = s_x2[j]; y2[s] = s_y2[j];
                ar[s] = (x2[s] - x1[s]) * (y2[s] - y1[s]);
                sv[s] = s_sc[j];
            } else { x1[s]=0.f; y1[s]=0.f; x2[s]=0.f; y2[s]=0.f; ar[s]=0.f; sv[s]=-1.0f; }
            act[s] = (sv[s] > CONF_T) ? 1 : 0;
            kf[s] = 0;
        }
        #pragma unroll
        for (int si = 0; si < 4; si++) {
            int lim = M_TOP - si * 64; if (lim > 64) lim = 64;
            for (int li = 0; li < lim; li++) {
                int a = __shfl(act[si], li);
                if (a) {
                    if (lane == li) kf[si] = 1;
                    float bx1 = __shfl(x1[si], li);
                    float by1 = __shfl(y1[si], li);
                    float bx2 = __shfl(x2[si], li);
                    float by2 = __shfl(y2[si], li);
                    float bar = __shfl(ar[si], li);
                    #pragma unroll
                    for (int s = 0; s < 4; s++) {
                        float xx1 = fmaxf(bx1, x1[s]);
                        float yy1 = fmaxf(by1, y1[s]);
                        float xx2 = fminf(bx2, x2[s]);
                        float yy2 = fminf(by2, y2[s]);
                        float inter = fmaxf(xx2 - xx1, 0.f) * fmaxf(yy2 - yy1, 0.f);
                        float uni = (ar[s] - inter) + bar;
                        float iou = inter / uni;
                        if (!(iou <= NMS_T)) act[s] = 0;   // NaN suppresses
                    }
                }
            }
        }
        unsigned long long ball[4];
        int total = 0;
        #pragma unroll
        for (int s = 0; s < 4; s++) { ball[s] = __ballot(kf[s] != 0); total += (int)__popcll(ball[s]); }
        int base = 0;
        if (lane == 0 && total > 0) base = atomicAdd(&pcnt[b], total);
        base = __shfl(base, 0);
        unsigned long long lower = (lane == 0) ? 0ull : (~0ull >> (64 - lane));
        int off = base;
        #pragma unroll
        for (int s = 0; s < 4; s++) {
            if (kf[s]) {
                int pos = off + (int)__popcll(ball[s] & lower);
                cmpval[(size_t)b * M + pos] = sv[s];
                cmpidx[(size_t)b * M + pos] = c * M_TOP + s * 64 + lane;
            }
            off += (int)__popcll(ball[s]);
        }
    }
}

// ---------------- Kernel E: top-200 of positives -> compact (val,idx) list ----------
__global__ __launch_bounds__(256) void gtop_kernel(
        const float* __restrict__ cmpval, const int* __restrict__ cmpidx,
        const int* __restrict__ pcnt, float* __restrict__ gl_val,
        int* __restrict__ gl_idx, int* __restrict__ gl_cnt, int M) {
    int b = blockIdx.x;
    int tid = threadIdx.x;
    int P = pcnt[b];
    const float* cv = cmpval + (size_t)b * M;
    const int*   ci = cmpidx + (size_t)b * M;
    if (P <= M_TOP) {
        for (int i = tid; i < P; i += 256) {
            gl_val[b * M_TOP + i] = cv[i];
            gl_idx[b * M_TOP + i] = ci[i];
        }
        if (tid == 0) gl_cnt[b] = P;
        return;
    }
    __shared__ uint32_t hist[256];
    __shared__ uint32_t s_prefix, s_want;
    __shared__ int tiebuf[256];
    __shared__ uint32_t ntie, wcnt;
    __shared__ int cutoff;
    if (tid == 0) { s_prefix = 0; s_want = M_TOP; }
    for (int pass = 0; pass < 4; pass++) {
        hist[tid] = 0;
        __syncthreads();
        uint32_t prefix = s_prefix;
        int shift = 24 - 8 * pass;
        for (int i = tid; i < P; i += 256) {
            uint32_t k = fkey(cv[i]);
            bool ok = (pass == 0) || ((k >> (shift + 8)) == (prefix >> (shift + 8)));
            if (ok) atomicAdd(&hist[(k >> shift) & 255u], 1u);
        }
        __syncthreads();
        if (tid == 0) {
            uint32_t want = s_want, cum = 0; int bin = 0;
            for (int bb = 255; bb >= 0; bb--) {
                if (cum + hist[bb] >= want) { bin = bb; break; }
                cum += hist[bb];
            }
            s_want = want - cum;
            s_prefix = prefix | ((uint32_t)bin << shift);
        }
        __syncthreads();
    }
    uint32_t kth = s_prefix, rfin = s_want;
    if (tid == 0) { ntie = 0; cutoff = -1; wcnt = 0; }
    __syncthreads();
    for (int i = tid; i < P; i += 256) {
        if (fkey(cv[i]) == kth) { uint32_t p = atomicAdd(&ntie, 1u); if (p < 256) tiebuf[p] = ci[i]; }
    }
    __syncthreads();
    uint32_t nt = min(ntie, 256u);
    if (tid < (int)nt) {
        int mine = tiebuf[tid];
        uint32_t rk = 0;
        for (uint32_t j = 0; j < nt; j++) if (tiebuf[j] < mine) rk++;
        if (rk == rfin - 1) cutoff = mine;
    }
    __syncthreads();
    int cut = cutoff;
    for (int i = tid; i < P; i += 256) {
        uint32_t k = fkey(cv[i]);
        if (k > kth || (k == kth && ci[i] <= cut)) {
            uint32_t p = atomicAdd(&wcnt, 1u);
            gl_val[b * M_TOP + p] = cv[i];
            gl_idx[b * M_TOP + p] = ci[i];
        }
    }
    if (tid == 0) gl_cnt[b] = M_TOP;
}

// ---------------- Kernel F: per-class sort + FULL output write (no memset) ----------
__global__ __launch_bounds__(256) void out_kernel(
        const float* __restrict__ gl_val, const int* __restrict__ gl_idx,
        const int* __restrict__ gl_cnt, const float* __restrict__ cand,
        float* __restrict__ out, int C, int Cm1) {
    int row = blockIdx.x;   // b*C + cc
    int b = row / C, cc = row % C;
    int tid = threadIdx.x;
    size_t oslab = (size_t)row * M_TOP * 5;
    if (cc == 0) {
        for (int i = tid; i < M_TOP * 5; i += 256) out[oslab + i] = 0.0f;
        return;
    }
    int c = cc - 1;
    __shared__ float lv[M_TOP];
    __shared__ int   lm[M_TOP];
    __shared__ uint32_t nloc;
    if (tid == 0) nloc = 0;
    __syncthreads();
    int cnt = gl_cnt[b];
    for (int i = tid; i < cnt; i += 256) {
        int idx = gl_idx[b * M_TOP + i];
        if (idx / M_TOP == c) {
            uint32_t p = atomicAdd(&nloc, 1u);
            lv[p] = gl_val[b * M_TOP + i];
            lm[p] = idx % M_TOP;
        }
    }
    __syncthreads();
    int nc = (int)nloc;
    if (tid < M_TOP) {
        if (tid < nc) {
            float v = lv[tid]; int m = lm[tid];
            int rk = 0;
            for (int j = 0; j < nc; j++)
                if (lv[j] > v || (lv[j] == v && lm[j] < m)) rk++;
            float4 bb = ((const float4*)cand)[((size_t)(b * Cm1 + c)) * M_TOP + m];
            size_t o = oslab + (size_t)rk * 5;
            out[o] = v; out[o + 1] = bb.x; out[o + 2] = bb.y;
            out[o + 3] = bb.z; out[o + 4] = bb.w;
        } else {
            size_t o = oslab + (size_t)tid * 5;
            out[o] = 0.f; out[o + 1] = 0.f; out[o + 2] = 0.f;
            out[o + 3] = 0.f; out[o + 4] = 0.f;
        }
    }
}

extern "C" void kernel_launch(void* const* d_in, const int* in_sizes, int n_in,
                              void* d_out, int out_size, void* d_ws, size_t ws_size,
                              hipStream_t stream) {
    const float* loc  = (const float*)d_in[0];
    const float* conf = (const float*)d_in[1];
    const float* dbox = (const float*)d_in[2];
    int N   = in_sizes[2] / 4;
    int B   = in_sizes[0] / (4 * N);
    int C   = in_sizes[1] / (B * N);
    int Cm1 = C - 1;
    int M   = Cm1 * M_TOP;                 // 16000 per batch

    char* ws = (char*)d_ws;
    size_t off = 0;
    auto alloc = [&](size_t bytes) -> char* {
        char* p = ws + off;
        off = (off + bytes + 255) & ~(size_t)255;
        return p;
    };
    float* sc     = (float*)alloc((size_t)B * Cm1 * N * sizeof(float));
    float* cand   = (float*)alloc((size_t)B * M * 4 * sizeof(float));
    int*   pcnt   = (int*)alloc((size_t)B * sizeof(int));
    float* cmpval = (float*)alloc((size_t)B * M * sizeof(float));
    int*   cmpidx = (int*)alloc((size_t)B * M * sizeof(int));
    float* gl_val = (float*)alloc((size_t)B * M_TOP * sizeof(float));
    int*   gl_idx = (int*)alloc((size_t)B * M_TOP * sizeof(int));
    int*   gl_cnt = (int*)alloc((size_t)B * sizeof(int));

    int bn = B * N;
    hipMemsetAsync(pcnt, 0, (size_t)B * sizeof(int), stream);
    softmax_kernel<<<(bn + SM_ROWS - 1) / SM_ROWS, SM_ROWS, 0, stream>>>(conf, sc, B, N, C);
    topk_kernel<<<B * Cm1, TK_BS, 0, stream>>>(sc, loc, dbox, cand, cmpval, cmpidx, pcnt,
                                               B, N, Cm1, M);
    gtop_kernel<<<B, 256, 0, stream>>>(cmpval, cmpidx, pcnt, gl_val, gl_idx, gl_cnt, M);
    out_kernel<<<B * C, 256, 0, stream>>>(gl_val, gl_idx, gl_cnt, cand, (float*)d_out, C, Cm1);
}